// Round 15
// baseline (793.303 us; speedup 1.0000x reference)
//
#include <hip/hip_runtime.h>
#include <hip/hip_bf16.h>

typedef float f32x4 __attribute__((ext_vector_type(4)));
typedef float f32x2 __attribute__((ext_vector_type(2)));
typedef short bf16x8 __attribute__((ext_vector_type(8)));

// ---- workspace layout (bytes) ----
static constexpr size_t WS_LOSSP = 0;         // double[2048]               -> 16384
static constexpr size_t WS_UMIN  = 16384;     // uint[65536] global min     -> 278528
static constexpr size_t WS_B32   = 294912;    // float[32768] np-exact B    -> 425984
static constexpr size_t WS_IDX   = 425984;    // int[65536]                 -> 688128
static constexpr size_t WS_CNT   = 688128;    // int[65536] cand counts     -> 950272
static constexpr size_t WS_LST   = 950272;    // ushort[65536*16] cand list -> 3047424
static constexpr size_t WS_XH    = 3145728;   // float[8*256*8192] 64MB     -> 70254592
static constexpr size_t WS_CBT   = 70254592;  // ushort bf16 frag-major     -> 87031808

#define DELTA 3.0e-4f

__device__ inline unsigned int fkey(float f) {
  unsigned int b = __float_as_uint(f); return (b & 0x80000000u) ? ~b : (b | 0x80000000u);
}
__device__ inline float funkey(unsigned int u) {
  unsigned int b = (u & 0x80000000u) ? (u ^ 0x80000000u) : ~u; return __uint_as_float(b);
}

// numpy pairwise_sum of 256 SQUARES, AVX512 width-16 emulation
__device__ inline float np_pw256sq(const float* p, int stride) {
#pragma clang fp contract(off)
  float h2[2];
#pragma unroll
  for (int hh = 0; hh < 2; ++hh) {
    const float* q = p + (size_t)(hh * 128) * stride;
    float V[16];
#pragma unroll
    for (int i = 0; i < 16; ++i) {
      float e[8];
#pragma unroll
      for (int j = 0; j < 8; ++j) { float x = q[(size_t)(j * 16 + i) * stride]; e[j] = x * x; }
      float t01 = e[0] + e[1], t23 = e[2] + e[3], t45 = e[4] + e[5], t67 = e[6] + e[7];
      float ta = t01 + t23, tb = t45 + t67;
      V[i] = ta + tb;
    }
    float u[8];
#pragma unroll
    for (int i = 0; i < 8; ++i) u[i] = V[i] + V[8 + i];
    float w[4];
#pragma unroll
    for (int i = 0; i < 4; ++i) w[i] = u[i] + u[4 + i];
    float wa = w[0] + w[2], wb = w[1] + w[3];
    h2[hh] = wa + wb;
  }
  return h2[0] + h2[1];
}

// ---------- np-exact codebook row norms ----------
__global__ __launch_bounds__(256) void k_cbnormB(const float* __restrict__ cb,
                                                 float* __restrict__ B32) {
  int row = blockIdx.x * 256 + threadIdx.x;      // grid 128 -> 32768 rows
  B32[row] = np_pw256sq(cb + (size_t)row * 256, 1);
}

// ---------- bf16 codebooks, FRAGMENT-MAJOR: [m][kt(256)][chunk p(512)] x 16B ----------
__global__ __launch_bounds__(256) void k_cbb(const float* __restrict__ cb,
                                             unsigned short* __restrict__ cbb) {
  int bx = blockIdx.x;                 // grid 2048 = m(8) * kt(256)
  int m = bx >> 8, kt = bx & 255;
  const float* src = cb + ((size_t)m * 4096 + kt * 16) * 256;
  unsigned short* dst = cbb + ((size_t)(m * 256 + kt)) * 4096;
  int tid = threadIdx.x;
#pragma unroll
  for (int h = 0; h < 2; ++h) {
    int p = tid + h * 256;
    int cs = p >> 6, lane = p & 63, row = lane & 15, grp = lane >> 4;
    const float* s = src + (size_t)row * 256 + grp * 8 + cs * 32;
    f32x4 v0 = *(const f32x4*)s;
    f32x4 v1 = *(const f32x4*)(s + 4);
    union { unsigned short us[8]; uint4 u; } o;
#pragma unroll
    for (int j = 0; j < 4; ++j) {
      __hip_bfloat16 h0 = __float2bfloat16(v0[j]);
      __hip_bfloat16 h1 = __float2bfloat16(v1[j]);
      o.us[j]     = *reinterpret_cast<unsigned short*>(&h0);
      o.us[4 + j] = *reinterpret_cast<unsigned short*>(&h1);
    }
    *(uint4*)(dst + (size_t)p * 8) = o.u;
  }
}

// ---------- x-hat: np.einsum-exact (sequential d, no FMA), 16 ch/thread, f32x2 packed ----------
__global__ __launch_bounds__(256) void k_xhat(const float* __restrict__ slots,
                                              const float* __restrict__ Wp,
                                              const float* __restrict__ bp,
                                              float* __restrict__ XH) {
#pragma clang fp contract(off)
  int bx = blockIdx.x;                 // grid 4096 = m(8) * tt(512)
  int m = bx & 7, tt = bx >> 3;
  int t0 = tt * 16;
  __shared__ float Ls[16 * 260];       // [tok][d], stride 260 -> 2-way-free reads, 16B rows
  __shared__ float Wt[32 * 264];       // [d-chunk][256 ch + pad] rows 1056B
  int tid = threadIdx.x;
  {                                    // stage 16 tokens x 256 d (1024 f32x4)
#pragma unroll
    for (int i = 0; i < 4; ++i) {
      int f = tid + 256 * i;
      int r = f >> 6, seg = f & 63;
      *(f32x4*)&Ls[r * 260 + seg * 4] =
          *(const f32x4*)(slots + (size_t)(t0 + r) * 2048 + m * 256 + seg * 4);
    }
  }
  int tl = tid & 15, g = tid >> 4;     // 16 tokens x 16 ch-groups (16 ch each)
  const float* lsrow = &Ls[tl * 260];
  const f32x4* wglob = (const f32x4*)(Wp + (size_t)m * 65536);
  f32x4 preg[8];
#pragma unroll
  for (int i = 0; i < 8; ++i) preg[i] = wglob[tid + 256 * i];   // chunk 0

  f32x2 acc[8];
#pragma unroll
  for (int i = 0; i < 8; ++i) acc[i] = f32x2{0.f, 0.f};

  for (int chunk = 0; chunk < 8; ++chunk) {
    __syncthreads();                   // prior chunk reads done (covers Ls staging, iter 0)
    {                                  // regs -> LDS (linear-ish, 2-way free)
      f32x4* wt4 = (f32x4*)Wt;
#pragma unroll
      for (int i = 0; i < 8; ++i) {
        int q = tid + 256 * i;
        wt4[(q >> 6) * 66 + (q & 63)] = preg[i];
      }
    }
    __syncthreads();
    if (chunk + 1 < 8) {               // prefetch next chunk (hidden under compute)
      const f32x4* src = wglob + (chunk + 1) * 2048;
#pragma unroll
      for (int i = 0; i < 8; ++i) preg[i] = src[tid + 256 * i];
    }
    const float* xs = lsrow + chunk * 32;
#pragma unroll 4
    for (int d = 0; d < 32; ++d) {
      float x = xs[d];
      f32x2 x2 = {x, x};
      const f32x4* wrow = (const f32x4*)&Wt[d * 264 + g * 16];
#pragma unroll
      for (int cq = 0; cq < 4; ++cq) {
        f32x4 wv = wrow[cq];
        f32x2 wlo = {wv[0], wv[1]};
        f32x2 whi = {wv[2], wv[3]};
        f32x2 plo = x2 * wlo;          // packed mul (IEEE-exact per lane)
        acc[cq * 2]     = acc[cq * 2]     + plo;   // packed add, strict d-order
        f32x2 phi = x2 * whi;
        acc[cq * 2 + 1] = acc[cq * 2 + 1] + phi;
      }
    }
  }
  int ch0 = g * 16;
  const float* bpb = bp + m * 256 + ch0;
  float* xgbase = XH + (size_t)m * 2097152 + t0 + tl;
#pragma unroll
  for (int i = 0; i < 8; ++i) {
    float v0 = acc[i][0] + bpb[i * 2];
    float v1 = acc[i][1] + bpb[i * 2 + 1];
    xgbase[(size_t)(ch0 + i * 2) * 8192]     = v0;
    xgbase[(size_t)(ch0 + i * 2 + 1) * 8192] = v1;
  }
}

// ---------- scan pass A: MFMA min, 3-deep counted-vmcnt pipeline ----------
// grid 1024 = tt(64) * ks(2) * m(8); block = 4 waves x 32 toks = 128 tokens, 128 k-tiles
__global__ __launch_bounds__(256) void k_scanA(const float* __restrict__ XH,
                                               const unsigned short* __restrict__ CBb,
                                               const float* __restrict__ B32,
                                               unsigned int* __restrict__ gumin) {
  int bx = blockIdx.x;
  int m = bx & 7, ks = (bx >> 3) & 1, tt = bx >> 4;
  int t0 = tt * 128, kt0 = ks * 128;
  __shared__ unsigned short Bt[3][2 * 4096];   // 3 bufs x 16KB (48KB)
  __shared__ unsigned int umin[128];
  int tid = threadIdx.x;
  if (tid < 128) umin[tid] = 0xFFFFFFFFu;
  int w = tid >> 6, l = tid & 63;
  int row = l & 15, grp = l >> 4;
  int tbase = w * 32;
  const float FINF = __builtin_inff();

  bf16x8 afrag[2][8];
  {
    const float* xbase = XH + (size_t)m * 2097152;
#pragma unroll
    for (int a = 0; a < 2; ++a)
#pragma unroll
      for (int cs = 0; cs < 8; ++cs) {
        union { short s[8]; bf16x8 v; } u;
#pragma unroll
        for (int j = 0; j < 8; ++j) {
          int c = cs * 32 + grp * 8 + j;
          float x = xbase[(size_t)c * 8192 + t0 + tbase + a * 16 + row];
          __hip_bfloat16 h = __float2bfloat16(x);
          u.s[j] = *reinterpret_cast<short*>(&h);
        }
        afrag[a][cs] = u.v;
      }
  }

  const uint4* cbsrc = (const uint4*)(CBb + (size_t)m * 1048576);
  const float* bvbase = B32 + m * 4096;
  auto stage = [&](int g, int b) {     // async: group g (16KB) -> Bt[b]; 4 loads/wave
    const uint4* s = cbsrc + (size_t)(kt0 + 2 * g) * 512;
    uint4* db = (uint4*)Bt[b];
#pragma unroll
    for (int h = 0; h < 4; ++h) {
      int c0 = h * 256 + w * 64;       // wave-uniform 1KB window; lane offset = l*16B (HW)
      __builtin_amdgcn_global_load_lds(
          (const __attribute__((address_space(1))) void*)(s + c0 + l),
          (__attribute__((address_space(3))) void*)(db + c0),
          16, 0, 0);
    }
  };

  float rmin[8];
#pragma unroll
  for (int sl = 0; sl < 8; ++sl) rmin[sl] = FINF;
  stage(0, 0); stage(1, 1);
  asm volatile("s_waitcnt vmcnt(4)" ::: "memory");   // group 0 resident
  __builtin_amdgcn_s_barrier();                      // also covers umin init
  for (int p = 0; p < 64; ++p) {
    int b = p % 3;
    if (p + 2 < 64) stage(p + 2, (p + 2) % 3);       // buf free since phase-p barrier
#pragma unroll
    for (int t = 0; t < 2; ++t) {
      int kt = kt0 + 2 * p + t;
      float Bv = bvbase[kt * 16 + row];
      f32x4 acc[2] = {f32x4{0.f,0.f,0.f,0.f}, f32x4{0.f,0.f,0.f,0.f}};
#pragma unroll
      for (int cs = 0; cs < 8; ++cs) {
        bf16x8 bf = *(const bf16x8*)&Bt[b][t * 4096 + cs * 512 + l * 8];
        acc[0] = __builtin_amdgcn_mfma_f32_16x16x32_bf16(afrag[0][cs], bf, acc[0], 0, 0, 0);
        acc[1] = __builtin_amdgcn_mfma_f32_16x16x32_bf16(afrag[1][cs], bf, acc[1], 0, 0, 0);
      }
#pragma unroll
      for (int a = 0; a < 2; ++a)
#pragma unroll
        for (int r = 0; r < 4; ++r)
          rmin[a * 4 + r] = fminf(rmin[a * 4 + r], fmaf(-2.0f, acc[a][r], Bv));
    }
    if (p < 62) {                      // counted: group p+1 landed, p+2 may still fly
      asm volatile("s_waitcnt vmcnt(4)" ::: "memory");
      __builtin_amdgcn_s_barrier();
    } else if (p == 62) {
      asm volatile("s_waitcnt vmcnt(0)" ::: "memory");
      __builtin_amdgcn_s_barrier();
    }
  }
#pragma unroll
  for (int a = 0; a < 2; ++a)
#pragma unroll
    for (int r = 0; r < 4; ++r)
      atomicMin(&umin[tbase + a * 16 + grp * 4 + r], fkey(rmin[a * 4 + r]));
  __syncthreads();
  if (tid < 128) atomicMin(&gumin[(size_t)(t0 + tid) * 8 + m], umin[tid]);
}

// ---------- scan pass B: recompute vs FINAL threshold, 3-deep counted-vmcnt pipeline ----------
__global__ __launch_bounds__(256) void k_scanB(const float* __restrict__ XH,
                                               const unsigned short* __restrict__ CBb,
                                               const float* __restrict__ B32,
                                               const unsigned int* __restrict__ gumin,
                                               int* __restrict__ cnts,
                                               unsigned short* __restrict__ lists) {
  int bx = blockIdx.x;
  int m = bx & 7, ks = (bx >> 3) & 1, tt = bx >> 4;
  int t0 = tt * 128, kt0 = ks * 128;
  __shared__ unsigned short Bt[3][2 * 4096];   // 48KB
  __shared__ int lcnt[128];
  __shared__ unsigned short llist[128][16];
  int tid = threadIdx.x;
  if (tid < 128) lcnt[tid] = 0;
  int w = tid >> 6, l = tid & 63;
  int row = l & 15, grp = l >> 4;
  int tbase = w * 32;

  bf16x8 afrag[2][8];
  {
    const float* xbase = XH + (size_t)m * 2097152;
#pragma unroll
    for (int a = 0; a < 2; ++a)
#pragma unroll
      for (int cs = 0; cs < 8; ++cs) {
        union { short s[8]; bf16x8 v; } u;
#pragma unroll
        for (int j = 0; j < 8; ++j) {
          int c = cs * 32 + grp * 8 + j;
          float x = xbase[(size_t)c * 8192 + t0 + tbase + a * 16 + row];
          __hip_bfloat16 h = __float2bfloat16(x);
          u.s[j] = *reinterpret_cast<short*>(&h);
        }
        afrag[a][cs] = u.v;
      }
  }
  float thr[8];
#pragma unroll
  for (int a = 0; a < 2; ++a)
#pragma unroll
    for (int r = 0; r < 4; ++r) {
      int tok = t0 + tbase + a * 16 + grp * 4 + r;
      thr[a * 4 + r] = funkey(gumin[(size_t)tok * 8 + m]) + DELTA;   // final (post-scanA)
    }

  const uint4* cbsrc = (const uint4*)(CBb + (size_t)m * 1048576);
  const float* bvbase = B32 + m * 4096;
  auto stage = [&](int g, int b) {
    const uint4* s = cbsrc + (size_t)(kt0 + 2 * g) * 512;
    uint4* db = (uint4*)Bt[b];
#pragma unroll
    for (int h = 0; h < 4; ++h) {
      int c0 = h * 256 + w * 64;
      __builtin_amdgcn_global_load_lds(
          (const __attribute__((address_space(1))) void*)(s + c0 + l),
          (__attribute__((address_space(3))) void*)(db + c0),
          16, 0, 0);
    }
  };

  stage(0, 0); stage(1, 1);
  asm volatile("s_waitcnt vmcnt(4)" ::: "memory");
  __builtin_amdgcn_s_barrier();                      // also covers lcnt init
  for (int p = 0; p < 64; ++p) {
    int b = p % 3;
    if (p + 2 < 64) stage(p + 2, (p + 2) % 3);
#pragma unroll
    for (int t = 0; t < 2; ++t) {
      int kt = kt0 + 2 * p + t;
      float Bv = bvbase[kt * 16 + row];
      f32x4 acc[2] = {f32x4{0.f,0.f,0.f,0.f}, f32x4{0.f,0.f,0.f,0.f}};
#pragma unroll
      for (int cs = 0; cs < 8; ++cs) {
        bf16x8 bf = *(const bf16x8*)&Bt[b][t * 4096 + cs * 512 + l * 8];
        acc[0] = __builtin_amdgcn_mfma_f32_16x16x32_bf16(afrag[0][cs], bf, acc[0], 0, 0, 0);
        acc[1] = __builtin_amdgcn_mfma_f32_16x16x32_bf16(afrag[1][cs], bf, acc[1], 0, 0, 0);
      }
      int k = (kt << 4) + row;
#pragma unroll
      for (int a = 0; a < 2; ++a)
#pragma unroll
        for (int r = 0; r < 4; ++r) {
          float s = fmaf(-2.0f, acc[a][r], Bv);
          if (s <= thr[a * 4 + r]) {
            int tok = tbase + a * 16 + grp * 4 + r;
            int pos = atomicAdd(&lcnt[tok], 1);
            if (pos < 16) llist[tok][pos] = (unsigned short)k;
          }
        }
    }
    if (p < 62) {
      asm volatile("s_waitcnt vmcnt(4)" ::: "memory");
      __builtin_amdgcn_s_barrier();
    } else if (p == 62) {
      asm volatile("s_waitcnt vmcnt(0)" ::: "memory");
      __builtin_amdgcn_s_barrier();
    }
  }
  __syncthreads();                     // all inserts visible before flush
  // flush: accumulate into global cnts/lists (two ks-blocks share each token)
  if (tid < 128) {
    int n = lcnt[tid];
    if (n > 0) {
      size_t t8m = (size_t)(t0 + tid) * 8 + m;
      int base = atomicAdd(&cnts[t8m], n);
      int nc = n < 16 ? n : 16;
      for (int i = 0; i < nc && base + i < 16; ++i)
        lists[t8m * 16 + base + i] = llist[tid][i];
    }
  }
}

// ---------- np-f32-exact final selection among candidates ----------
__global__ __launch_bounds__(256) void k_select(const float* __restrict__ XH,
                                                const float* __restrict__ cb,
                                                const float* __restrict__ B32,
                                                const int* __restrict__ cnts,
                                                const unsigned short* __restrict__ lists,
                                                int* __restrict__ idxp) {
#pragma clang fp contract(off)
  int bx = blockIdx.x;                 // grid 1024 = tt(128) * m(8)
  int m = bx & 7, tt = bx >> 3;
  int t0 = tt * 64;
  __shared__ float XT2[256 * 65];      // padded [c][t]
  __shared__ float Atok[64];
  __shared__ int ovlist[64];
  __shared__ int ovcnt;
  __shared__ float bvD[64];
  __shared__ int bvK[64];
  int tid = threadIdx.x;
  const float* xsrc = XH + (size_t)m * 2097152;
#pragma unroll
  for (int i = 0; i < 16; ++i) {
    int f = tid + 256 * i;
    int c = f >> 4, to = (f & 15) * 4;
    f32x4 v = *(const f32x4*)(xsrc + (size_t)c * 8192 + t0 + to);
    XT2[c*65+to+0]=v[0]; XT2[c*65+to+1]=v[1]; XT2[c*65+to+2]=v[2]; XT2[c*65+to+3]=v[3];
  }
  if (tid == 0) ovcnt = 0;
  __syncthreads();
  if (tid < 64) Atok[tid] = np_pw256sq(&XT2[tid], 65);   // np.sum(x*x) emulation
  __syncthreads();
  int q = tid >> 2, j = tid & 3;       // 64 quads (token t0+q) x 4 SSE lanes
  const float* cbm = cb + (size_t)m * 1048576;

  auto dist_np = [&](int k, int qq, float A) -> float {
#pragma clang fp contract(off)
    const float* row = cbm + (size_t)k * 256;
    float s = 0.0f;
    for (int i8 = 0; i8 < 256; i8 += 8) {
      float p0 = XT2[(i8 + j) * 65 + qq] * row[i8 + j];
      s = s + p0;
      float p1 = XT2[(i8 + 4 + j) * 65 + qq] * row[i8 + 4 + j];
      s = s + p1;
    }
    float o  = __shfl_xor(s, 1, 64);
    float ts = s + o;
    float o2 = __shfl_xor(ts, 2, 64);
    float red = ts + o2;               // (s0+s1)+(s2+s3)
    float T1 = A + B32[m * 4096 + k];  // fl(A + Bk)
    return T1 - 2.0f * red;            // fl(T1 - fl(2E))
  };

  int t8m = (t0 + q) * 8 + m;
  int n = cnts[t8m];
  float A = Atok[q];
  if (n <= 16) {
    float best = __builtin_inff();
    int bk = 0;
    for (int ci = 0; ci < n; ++ci) {
      int k = (int)lists[(size_t)t8m * 16 + ci] & 4095;
      float d2 = dist_np(k, q, A);
      if (d2 < best || (d2 == best && k < bk)) { best = d2; bk = k; }
    }
    if (j == 0) idxp[t8m] = bk;
  } else {
    if (j == 0) { int pos = atomicAdd(&ovcnt, 1); ovlist[pos] = q; }
  }
  __syncthreads();
  int ovn = ovcnt;
  for (int e = 0; e < ovn; ++e) {      // block-cooperative full scan per overflow token
    int qq = ovlist[e];
    float Aq = Atok[qq];
    float bd = __builtin_inff(); int bk2 = 0;
    for (int it = 0; it < 64; ++it) {
      int k = it * 64 + q;
      float d2 = dist_np(k, qq, Aq);
      if (d2 < bd) { bd = d2; bk2 = k; }
    }
    if (j == 0) { bvD[q] = bd; bvK[q] = bk2; }
    __syncthreads();
    if (tid == 0) {
      float bb = bvD[0]; int kk2 = bvK[0];
      for (int r = 1; r < 64; ++r) {
        if (bvD[r] < bb || (bvD[r] == bb && bvK[r] < kk2)) { bb = bvD[r]; kk2 = bvK[r]; }
      }
      idxp[(t0 + qq) * 8 + m] = kk2;
    }
    __syncthreads();
  }
}

// ---------- out = q@Wo + bo (f32), plus per-block loss partials ----------
__global__ __launch_bounds__(256) void k_out(const float* __restrict__ cb,
                                             const float* __restrict__ Wo,
                                             const float* __restrict__ bo,
                                             const float* __restrict__ XH,
                                             const int* __restrict__ idxp,
                                             float* __restrict__ outp,
                                             double* __restrict__ lossp) {
  int bx = blockIdx.x;                 // grid 2048 = tt(256) * m(8)
  int m = bx & 7, tt = bx >> 3;
  int t0 = tt * 32;
  __shared__ float qT[256 * 32];       // [c][t] 32KB
  __shared__ float Wl[64 * 256];       // [c][d] 64KB
  __shared__ double red[256];
  int tid = threadIdx.x;
  {
    int tok = tid & 31, g = tid >> 5;
    int ix = idxp[(size_t)(t0 + tok) * 8 + m] & 4095;
    const float* qrow = cb + ((size_t)m * 4096 + ix) * 256;
#pragma unroll
    for (int i = 0; i < 8; ++i) {
      int c = (g * 8 + i) * 4;
      f32x4 v = *(const f32x4*)(qrow + c);
      qT[(c+0)*32+tok]=v[0]; qT[(c+1)*32+tok]=v[1]; qT[(c+2)*32+tok]=v[2]; qT[(c+3)*32+tok]=v[3];
    }
  }
  int tg = tid & 7, dg = tid >> 3;     // 8 tok-groups(4 tok) x 32 d-groups(8 d)
  float acc[4][8] = {};
  const float* wbase = Wo + (size_t)m * 65536;
  for (int c4 = 0; c4 < 4; ++c4) {
    __syncthreads();
#pragma unroll
    for (int i = 0; i < 16; ++i) {
      int f = tid + 256 * i;
      int cr = f >> 6, doff = (f & 63) * 4;
      *(f32x4*)&Wl[f * 4] = *(const f32x4*)(wbase + (size_t)(c4 * 64 + cr) * 256 + doff);
    }
    __syncthreads();
#pragma unroll 4
    for (int c = 0; c < 64; ++c) {
      f32x4 q4 = *(const f32x4*)&qT[(c4 * 64 + c) * 32 + tg * 4];
      f32x4 w0 = *(const f32x4*)&Wl[c * 256 + dg * 8];
      f32x4 w1 = *(const f32x4*)&Wl[c * 256 + dg * 8 + 4];
#pragma unroll
      for (int i = 0; i < 4; ++i) {
        acc[i][0]+=q4[i]*w0[0]; acc[i][1]+=q4[i]*w0[1]; acc[i][2]+=q4[i]*w0[2]; acc[i][3]+=q4[i]*w0[3];
        acc[i][4]+=q4[i]*w1[0]; acc[i][5]+=q4[i]*w1[1]; acc[i][6]+=q4[i]*w1[2]; acc[i][7]+=q4[i]*w1[3];
      }
    }
  }
#pragma unroll
  for (int i = 0; i < 4; ++i) {
    int t = t0 + tg * 4 + i;
    f32x4 lo, hi;
#pragma unroll
    for (int jj = 0; jj < 4; ++jj) {
      lo[jj] = acc[i][jj]     + bo[m * 256 + dg * 8 + jj];
      hi[jj] = acc[i][jj + 4] + bo[m * 256 + dg * 8 + 4 + jj];
    }
    float* dst = outp + (size_t)t * 2048 + m * 256 + dg * 8;
    *(f32x4*)(dst)     = lo;
    *(f32x4*)(dst + 4) = hi;
  }
  float lp = 0.0f;
  {
    int ltok = tid & 31, cg2 = tid >> 5;
    const float* xg = XH + (size_t)m * 2097152 + t0 + ltok;
    for (int c = cg2 * 32; c < cg2 * 32 + 32; ++c) {
      float qv = qT[c * 32 + ltok];
      float xv = xg[(size_t)c * 8192];
      float d = qv - xv; lp += d * d;
    }
  }
  red[tid] = (double)lp;
  __syncthreads();
  for (int off = 128; off; off >>= 1) { if (tid < off) red[tid] += red[tid + off]; __syncthreads(); }
  if (tid == 0) lossp[bx] = red[0];
}

// ---------- finalize loss (f32 at outp[16777216]) ----------
__global__ void k_final(const double* __restrict__ lossp, float* __restrict__ outp) {
  __shared__ double red[256];
  int tid = threadIdx.x;
  double s = 0.0;
  for (int i = 0; i < 8; ++i) s += lossp[tid + 256 * i];
  red[tid] = s; __syncthreads();
  for (int off = 128; off; off >>= 1) { if (tid < off) red[tid] += red[tid + off]; __syncthreads(); }
  if (tid == 0) outp[16777216] = (float)(1.25 * red[0] / 16777216.0);
}

// ---------- idx -> f32 ----------
__global__ void k_idxout(const int* __restrict__ idxp, float* __restrict__ outp) {
  int i = blockIdx.x * 256 + threadIdx.x;
  outp[16777217 + i] = (float)idxp[i];
}

extern "C" void kernel_launch(void* const* d_in, const int* in_sizes, int n_in,
                              void* d_out, int out_size, void* d_ws, size_t ws_size,
                              hipStream_t stream) {
  (void)in_sizes; (void)n_in; (void)out_size; (void)ws_size;
  const float* slots = (const float*)d_in[0];
  const float* Wp    = (const float*)d_in[1];
  const float* bp    = (const float*)d_in[2];
  const float* cb    = (const float*)d_in[3];
  const float* Wo    = (const float*)d_in[4];
  const float* bo    = (const float*)d_in[5];
  float* outp = (float*)d_out;
  char* ws = (char*)d_ws;
  double*         lossp = (double*)(ws + WS_LOSSP);
  unsigned int*   gumin = (unsigned int*)(ws + WS_UMIN);
  float*          B32   = (float*)(ws + WS_B32);
  int*            idxp  = (int*)(ws + WS_IDX);
  int*            cnts  = (int*)(ws + WS_CNT);
  unsigned short* lists = (unsigned short*)(ws + WS_LST);
  float*          XH    = (float*)(ws + WS_XH);
  unsigned short* CBb   = (unsigned short*)(ws + WS_CBT);

  hipMemsetAsync(gumin, 0xFF, 65536 * sizeof(unsigned int), stream);
  hipMemsetAsync(cnts,  0,    65536 * sizeof(int), stream);
  k_cbnormB<<<128,  256, 0, stream>>>(cb, B32);
  k_cbb    <<<2048, 256, 0, stream>>>(cb, CBb);
  k_xhat   <<<4096, 256, 0, stream>>>(slots, Wp, bp, XH);
  k_scanA  <<<1024, 256, 0, stream>>>(XH, CBb, B32, gumin);
  k_scanB  <<<1024, 256, 0, stream>>>(XH, CBb, B32, gumin, cnts, lists);
  k_select <<<1024, 256, 0, stream>>>(XH, cb, B32, cnts, lists, idxp);
  k_out    <<<2048, 256, 0, stream>>>(cb, Wo, bo, XH, idxp, outp, lossp);
  k_final  <<<1,    256, 0, stream>>>(lossp, outp);
  k_idxout <<<256,  256, 0, stream>>>(idxp, outp);
}

// Round 16
// 731.501 us; speedup vs baseline: 1.0845x; 1.0845x over previous
//
#include <hip/hip_runtime.h>
#include <hip/hip_bf16.h>

typedef float f32x4 __attribute__((ext_vector_type(4)));
typedef float f32x2 __attribute__((ext_vector_type(2)));
typedef short bf16x8 __attribute__((ext_vector_type(8)));

// ---- workspace layout (bytes) ----
static constexpr size_t WS_LOSSP = 0;         // double[2048]               -> 16384
static constexpr size_t WS_UMIN  = 16384;     // uint[65536] global min     -> 278528
static constexpr size_t WS_B32   = 294912;    // float[32768] np-exact B    -> 425984
static constexpr size_t WS_IDX   = 425984;    // int[65536]                 -> 688128
static constexpr size_t WS_CNT   = 688128;    // int[65536] cand counts     -> 950272
static constexpr size_t WS_LST   = 950272;    // ushort[65536*16] cand list -> 3047424
static constexpr size_t WS_XH    = 3145728;   // float[8*256*8192] 64MB     -> 70254592
static constexpr size_t WS_CBT   = 70254592;  // ushort bf16 frag-major     -> 87031808

#define DELTA 3.0e-4f

__device__ inline unsigned int fkey(float f) {
  unsigned int b = __float_as_uint(f); return (b & 0x80000000u) ? ~b : (b | 0x80000000u);
}
__device__ inline float funkey(unsigned int u) {
  unsigned int b = (u & 0x80000000u) ? (u ^ 0x80000000u) : ~u; return __uint_as_float(b);
}

// numpy pairwise_sum of 256 SQUARES, AVX512 width-16 emulation
__device__ inline float np_pw256sq(const float* p, int stride) {
#pragma clang fp contract(off)
  float h2[2];
#pragma unroll
  for (int hh = 0; hh < 2; ++hh) {
    const float* q = p + (size_t)(hh * 128) * stride;
    float V[16];
#pragma unroll
    for (int i = 0; i < 16; ++i) {
      float e[8];
#pragma unroll
      for (int j = 0; j < 8; ++j) { float x = q[(size_t)(j * 16 + i) * stride]; e[j] = x * x; }
      float t01 = e[0] + e[1], t23 = e[2] + e[3], t45 = e[4] + e[5], t67 = e[6] + e[7];
      float ta = t01 + t23, tb = t45 + t67;
      V[i] = ta + tb;
    }
    float u[8];
#pragma unroll
    for (int i = 0; i < 8; ++i) u[i] = V[i] + V[8 + i];
    float w[4];
#pragma unroll
    for (int i = 0; i < 4; ++i) w[i] = u[i] + u[4 + i];
    float wa = w[0] + w[2], wb = w[1] + w[3];
    h2[hh] = wa + wb;
  }
  return h2[0] + h2[1];
}

// ---------- np-exact codebook row norms ----------
__global__ __launch_bounds__(256) void k_cbnormB(const float* __restrict__ cb,
                                                 float* __restrict__ B32) {
  int row = blockIdx.x * 256 + threadIdx.x;      // grid 128 -> 32768 rows
  B32[row] = np_pw256sq(cb + (size_t)row * 256, 1);
}

// ---------- bf16 codebooks, FRAGMENT-MAJOR: [m][kt(256)][chunk p(512)] x 16B ----------
__global__ __launch_bounds__(256) void k_cbb(const float* __restrict__ cb,
                                             unsigned short* __restrict__ cbb) {
  int bx = blockIdx.x;                 // grid 2048 = m(8) * kt(256)
  int m = bx >> 8, kt = bx & 255;
  const float* src = cb + ((size_t)m * 4096 + kt * 16) * 256;
  unsigned short* dst = cbb + ((size_t)(m * 256 + kt)) * 4096;
  int tid = threadIdx.x;
#pragma unroll
  for (int h = 0; h < 2; ++h) {
    int p = tid + h * 256;
    int cs = p >> 6, lane = p & 63, row = lane & 15, grp = lane >> 4;
    const float* s = src + (size_t)row * 256 + grp * 8 + cs * 32;
    f32x4 v0 = *(const f32x4*)s;
    f32x4 v1 = *(const f32x4*)(s + 4);
    union { unsigned short us[8]; uint4 u; } o;
#pragma unroll
    for (int j = 0; j < 4; ++j) {
      __hip_bfloat16 h0 = __float2bfloat16(v0[j]);
      __hip_bfloat16 h1 = __float2bfloat16(v1[j]);
      o.us[j]     = *reinterpret_cast<unsigned short*>(&h0);
      o.us[4 + j] = *reinterpret_cast<unsigned short*>(&h1);
    }
    *(uint4*)(dst + (size_t)p * 8) = o.u;
  }
}

// ---------- x-hat: np.einsum-exact (sequential d, no FMA), 16 ch/thread, f32x2 packed ----------
__global__ __launch_bounds__(256) void k_xhat(const float* __restrict__ slots,
                                              const float* __restrict__ Wp,
                                              const float* __restrict__ bp,
                                              float* __restrict__ XH) {
#pragma clang fp contract(off)
  int bx = blockIdx.x;                 // grid 4096 = m(8) * tt(512)
  int m = bx & 7, tt = bx >> 3;
  int t0 = tt * 16;
  __shared__ float Ls[16 * 260];       // [tok][d], stride 260 -> 2-way-free reads, 16B rows
  __shared__ float Wt[32 * 264];       // [d-chunk][256 ch + pad] rows 1056B
  int tid = threadIdx.x;
  {                                    // stage 16 tokens x 256 d (1024 f32x4)
#pragma unroll
    for (int i = 0; i < 4; ++i) {
      int f = tid + 256 * i;
      int r = f >> 6, seg = f & 63;
      *(f32x4*)&Ls[r * 260 + seg * 4] =
          *(const f32x4*)(slots + (size_t)(t0 + r) * 2048 + m * 256 + seg * 4);
    }
  }
  int tl = tid & 15, g = tid >> 4;     // 16 tokens x 16 ch-groups (16 ch each)
  const float* lsrow = &Ls[tl * 260];
  const f32x4* wglob = (const f32x4*)(Wp + (size_t)m * 65536);
  f32x4 preg[8];
#pragma unroll
  for (int i = 0; i < 8; ++i) preg[i] = wglob[tid + 256 * i];   // chunk 0

  f32x2 acc[8];
#pragma unroll
  for (int i = 0; i < 8; ++i) acc[i] = f32x2{0.f, 0.f};

  for (int chunk = 0; chunk < 8; ++chunk) {
    __syncthreads();                   // prior chunk reads done (covers Ls staging, iter 0)
    {                                  // regs -> LDS (linear-ish, 2-way free)
      f32x4* wt4 = (f32x4*)Wt;
#pragma unroll
      for (int i = 0; i < 8; ++i) {
        int q = tid + 256 * i;
        wt4[(q >> 6) * 66 + (q & 63)] = preg[i];
      }
    }
    __syncthreads();
    if (chunk + 1 < 8) {               // prefetch next chunk (hidden under compute)
      const f32x4* src = wglob + (chunk + 1) * 2048;
#pragma unroll
      for (int i = 0; i < 8; ++i) preg[i] = src[tid + 256 * i];
    }
    const float* xs = lsrow + chunk * 32;
#pragma unroll 4
    for (int d = 0; d < 32; ++d) {
      float x = xs[d];
      f32x2 x2 = {x, x};
      const f32x4* wrow = (const f32x4*)&Wt[d * 264 + g * 16];
#pragma unroll
      for (int cq = 0; cq < 4; ++cq) {
        f32x4 wv = wrow[cq];
        f32x2 wlo = {wv[0], wv[1]};
        f32x2 whi = {wv[2], wv[3]};
        f32x2 plo = x2 * wlo;          // packed mul (IEEE-exact per lane)
        acc[cq * 2]     = acc[cq * 2]     + plo;   // packed add, strict d-order
        f32x2 phi = x2 * whi;
        acc[cq * 2 + 1] = acc[cq * 2 + 1] + phi;
      }
    }
  }
  int ch0 = g * 16;
  const float* bpb = bp + m * 256 + ch0;
  float* xgbase = XH + (size_t)m * 2097152 + t0 + tl;
#pragma unroll
  for (int i = 0; i < 8; ++i) {
    float v0 = acc[i][0] + bpb[i * 2];
    float v1 = acc[i][1] + bpb[i * 2 + 1];
    xgbase[(size_t)(ch0 + i * 2) * 8192]     = v0;
    xgbase[(size_t)(ch0 + i * 2 + 1) * 8192] = v1;
  }
}

// ---------- scan pass A: MFMA min, 64 tok/wave, 3-deep counted-vmcnt pipeline ----------
// grid 512 = tt(32) * ks(2) * m(8); block = 4 waves x 64 toks = 256 tokens, 128 k-tiles
__global__ __launch_bounds__(256, 2) void k_scanA(const float* __restrict__ XH,
                                                  const unsigned short* __restrict__ CBb,
                                                  const float* __restrict__ B32,
                                                  unsigned int* __restrict__ gumin) {
  int bx = blockIdx.x;
  int m = bx & 7, ks = (bx >> 3) & 1, tt = bx >> 4;
  int t0 = tt * 256, kt0 = ks * 128;
  __shared__ unsigned short Bt[3][2 * 4096];   // 3 bufs x 16KB (48KB)
  __shared__ unsigned int umin[256];
  int tid = threadIdx.x;
  umin[tid] = 0xFFFFFFFFu;
  int w = tid >> 6, l = tid & 63;
  int row = l & 15, grp = l >> 4;
  int tbase = w * 64;
  const float FINF = __builtin_inff();

  bf16x8 afrag[4][8];
  {
    const float* xbase = XH + (size_t)m * 2097152;
#pragma unroll
    for (int a = 0; a < 4; ++a)
#pragma unroll
      for (int cs = 0; cs < 8; ++cs) {
        union { short s[8]; bf16x8 v; } u;
#pragma unroll
        for (int j = 0; j < 8; ++j) {
          int c = cs * 32 + grp * 8 + j;
          float x = xbase[(size_t)c * 8192 + t0 + tbase + a * 16 + row];
          __hip_bfloat16 h = __float2bfloat16(x);
          u.s[j] = *reinterpret_cast<short*>(&h);
        }
        afrag[a][cs] = u.v;
      }
  }

  const uint4* cbsrc = (const uint4*)(CBb + (size_t)m * 1048576);
  const float* bvbase = B32 + m * 4096;
  auto stage = [&](int g, int b) {     // async: group g (16KB) -> Bt[b]; 4 loads/wave
    const uint4* s = cbsrc + (size_t)(kt0 + 2 * g) * 512;
    uint4* db = (uint4*)Bt[b];
#pragma unroll
    for (int h = 0; h < 4; ++h) {
      int c0 = h * 256 + w * 64;       // wave-uniform 1KB window; lane offset = l*16B (HW)
      __builtin_amdgcn_global_load_lds(
          (const __attribute__((address_space(1))) void*)(s + c0 + l),
          (__attribute__((address_space(3))) void*)(db + c0),
          16, 0, 0);
    }
  };

  float rmin[16];
#pragma unroll
  for (int sl = 0; sl < 16; ++sl) rmin[sl] = FINF;
  stage(0, 0); stage(1, 1);
  asm volatile("s_waitcnt vmcnt(4)" ::: "memory");   // group 0 resident
  __builtin_amdgcn_s_barrier();                      // also covers umin init
  for (int p = 0; p < 64; ++p) {
    int b = p % 3;
    if (p + 2 < 64) stage(p + 2, (p + 2) % 3);       // buf free since phase-p barrier
#pragma unroll
    for (int t = 0; t < 2; ++t) {
      int kt = kt0 + 2 * p + t;
      float Bv = bvbase[kt * 16 + row];
      f32x4 acc[4];
#pragma unroll
      for (int a = 0; a < 4; ++a) acc[a] = f32x4{0.f,0.f,0.f,0.f};
#pragma unroll
      for (int cs = 0; cs < 8; ++cs) {
        bf16x8 bf = *(const bf16x8*)&Bt[b][t * 4096 + cs * 512 + l * 8];
#pragma unroll
        for (int a = 0; a < 4; ++a)
          acc[a] = __builtin_amdgcn_mfma_f32_16x16x32_bf16(afrag[a][cs], bf, acc[a], 0, 0, 0);
      }
#pragma unroll
      for (int a = 0; a < 4; ++a)
#pragma unroll
        for (int r = 0; r < 4; ++r)
          rmin[a * 4 + r] = fminf(rmin[a * 4 + r], fmaf(-2.0f, acc[a][r], Bv));
    }
    if (p < 62) {                      // counted: group p+1 landed, p+2 may still fly
      asm volatile("s_waitcnt vmcnt(4)" ::: "memory");
      __builtin_amdgcn_s_barrier();
    } else if (p == 62) {
      asm volatile("s_waitcnt vmcnt(0)" ::: "memory");
      __builtin_amdgcn_s_barrier();
    }
  }
#pragma unroll
  for (int a = 0; a < 4; ++a)
#pragma unroll
    for (int r = 0; r < 4; ++r)
      atomicMin(&umin[tbase + a * 16 + grp * 4 + r], fkey(rmin[a * 4 + r]));
  __syncthreads();
  atomicMin(&gumin[(size_t)(t0 + tid) * 8 + m], umin[tid]);
}

// ---------- scan pass B: recompute vs FINAL threshold, 64 tok/wave, counted-vmcnt ----------
__global__ __launch_bounds__(256, 2) void k_scanB(const float* __restrict__ XH,
                                                  const unsigned short* __restrict__ CBb,
                                                  const float* __restrict__ B32,
                                                  const unsigned int* __restrict__ gumin,
                                                  int* __restrict__ cnts,
                                                  unsigned short* __restrict__ lists) {
  int bx = blockIdx.x;
  int m = bx & 7, ks = (bx >> 3) & 1, tt = bx >> 4;
  int t0 = tt * 256, kt0 = ks * 128;
  __shared__ unsigned short Bt[3][2 * 4096];   // 48KB
  __shared__ int lcnt[256];
  __shared__ unsigned short llist[256][16];
  int tid = threadIdx.x;
  lcnt[tid] = 0;
  int w = tid >> 6, l = tid & 63;
  int row = l & 15, grp = l >> 4;
  int tbase = w * 64;

  bf16x8 afrag[4][8];
  {
    const float* xbase = XH + (size_t)m * 2097152;
#pragma unroll
    for (int a = 0; a < 4; ++a)
#pragma unroll
      for (int cs = 0; cs < 8; ++cs) {
        union { short s[8]; bf16x8 v; } u;
#pragma unroll
        for (int j = 0; j < 8; ++j) {
          int c = cs * 32 + grp * 8 + j;
          float x = xbase[(size_t)c * 8192 + t0 + tbase + a * 16 + row];
          __hip_bfloat16 h = __float2bfloat16(x);
          u.s[j] = *reinterpret_cast<short*>(&h);
        }
        afrag[a][cs] = u.v;
      }
  }
  float thr[16];
#pragma unroll
  for (int a = 0; a < 4; ++a)
#pragma unroll
    for (int r = 0; r < 4; ++r) {
      int tok = t0 + tbase + a * 16 + grp * 4 + r;
      thr[a * 4 + r] = funkey(gumin[(size_t)tok * 8 + m]) + DELTA;   // final (post-scanA)
    }

  const uint4* cbsrc = (const uint4*)(CBb + (size_t)m * 1048576);
  const float* bvbase = B32 + m * 4096;
  auto stage = [&](int g, int b) {
    const uint4* s = cbsrc + (size_t)(kt0 + 2 * g) * 512;
    uint4* db = (uint4*)Bt[b];
#pragma unroll
    for (int h = 0; h < 4; ++h) {
      int c0 = h * 256 + w * 64;
      __builtin_amdgcn_global_load_lds(
          (const __attribute__((address_space(1))) void*)(s + c0 + l),
          (__attribute__((address_space(3))) void*)(db + c0),
          16, 0, 0);
    }
  };

  stage(0, 0); stage(1, 1);
  asm volatile("s_waitcnt vmcnt(4)" ::: "memory");
  __builtin_amdgcn_s_barrier();                      // also covers lcnt init
  for (int p = 0; p < 64; ++p) {
    int b = p % 3;
    if (p + 2 < 64) stage(p + 2, (p + 2) % 3);
#pragma unroll
    for (int t = 0; t < 2; ++t) {
      int kt = kt0 + 2 * p + t;
      float Bv = bvbase[kt * 16 + row];
      f32x4 acc[4];
#pragma unroll
      for (int a = 0; a < 4; ++a) acc[a] = f32x4{0.f,0.f,0.f,0.f};
#pragma unroll
      for (int cs = 0; cs < 8; ++cs) {
        bf16x8 bf = *(const bf16x8*)&Bt[b][t * 4096 + cs * 512 + l * 8];
#pragma unroll
        for (int a = 0; a < 4; ++a)
          acc[a] = __builtin_amdgcn_mfma_f32_16x16x32_bf16(afrag[a][cs], bf, acc[a], 0, 0, 0);
      }
      int k = (kt << 4) + row;
#pragma unroll
      for (int a = 0; a < 4; ++a)
#pragma unroll
        for (int r = 0; r < 4; ++r) {
          float s = fmaf(-2.0f, acc[a][r], Bv);
          if (s <= thr[a * 4 + r]) {
            int tok = tbase + a * 16 + grp * 4 + r;
            int pos = atomicAdd(&lcnt[tok], 1);
            if (pos < 16) llist[tok][pos] = (unsigned short)k;
          }
        }
    }
    if (p < 62) {
      asm volatile("s_waitcnt vmcnt(4)" ::: "memory");
      __builtin_amdgcn_s_barrier();
    } else if (p == 62) {
      asm volatile("s_waitcnt vmcnt(0)" ::: "memory");
      __builtin_amdgcn_s_barrier();
    }
  }
  __syncthreads();                     // all inserts visible before flush
  // flush: accumulate into global cnts/lists (two ks-blocks share each token)
  {
    int n = lcnt[tid];
    if (n > 0) {
      size_t t8m = (size_t)(t0 + tid) * 8 + m;
      int base = atomicAdd(&cnts[t8m], n);
      int nc = n < 16 ? n : 16;
      for (int i = 0; i < nc && base + i < 16; ++i)
        lists[t8m * 16 + base + i] = llist[tid][i];
    }
  }
}

// ---------- np-f32-exact final selection among candidates ----------
__global__ __launch_bounds__(256) void k_select(const float* __restrict__ XH,
                                                const float* __restrict__ cb,
                                                const float* __restrict__ B32,
                                                const int* __restrict__ cnts,
                                                const unsigned short* __restrict__ lists,
                                                int* __restrict__ idxp) {
#pragma clang fp contract(off)
  int bx = blockIdx.x;                 // grid 1024 = tt(128) * m(8)
  int m = bx & 7, tt = bx >> 3;
  int t0 = tt * 64;
  __shared__ float XT2[256 * 65];      // padded [c][t]
  __shared__ float Atok[64];
  __shared__ int ovlist[64];
  __shared__ int ovcnt;
  __shared__ float bvD[64];
  __shared__ int bvK[64];
  int tid = threadIdx.x;
  const float* xsrc = XH + (size_t)m * 2097152;
#pragma unroll
  for (int i = 0; i < 16; ++i) {
    int f = tid + 256 * i;
    int c = f >> 4, to = (f & 15) * 4;
    f32x4 v = *(const f32x4*)(xsrc + (size_t)c * 8192 + t0 + to);
    XT2[c*65+to+0]=v[0]; XT2[c*65+to+1]=v[1]; XT2[c*65+to+2]=v[2]; XT2[c*65+to+3]=v[3];
  }
  if (tid == 0) ovcnt = 0;
  __syncthreads();
  if (tid < 64) Atok[tid] = np_pw256sq(&XT2[tid], 65);   // np.sum(x*x) emulation
  __syncthreads();
  int q = tid >> 2, j = tid & 3;       // 64 quads (token t0+q) x 4 SSE lanes
  const float* cbm = cb + (size_t)m * 1048576;

  auto dist_np = [&](int k, int qq, float A) -> float {
#pragma clang fp contract(off)
    const float* row = cbm + (size_t)k * 256;
    float s = 0.0f;
    for (int i8 = 0; i8 < 256; i8 += 8) {
      float p0 = XT2[(i8 + j) * 65 + qq] * row[i8 + j];
      s = s + p0;
      float p1 = XT2[(i8 + 4 + j) * 65 + qq] * row[i8 + 4 + j];
      s = s + p1;
    }
    float o  = __shfl_xor(s, 1, 64);
    float ts = s + o;
    float o2 = __shfl_xor(ts, 2, 64);
    float red = ts + o2;               // (s0+s1)+(s2+s3)
    float T1 = A + B32[m * 4096 + k];  // fl(A + Bk)
    return T1 - 2.0f * red;            // fl(T1 - fl(2E))
  };

  int t8m = (t0 + q) * 8 + m;
  int n = cnts[t8m];
  float A = Atok[q];
  if (n <= 16) {
    float best = __builtin_inff();
    int bk = 0;
    for (int ci = 0; ci < n; ++ci) {
      int k = (int)lists[(size_t)t8m * 16 + ci] & 4095;
      float d2 = dist_np(k, q, A);
      if (d2 < best || (d2 == best && k < bk)) { best = d2; bk = k; }
    }
    if (j == 0) idxp[t8m] = bk;
  } else {
    if (j == 0) { int pos = atomicAdd(&ovcnt, 1); ovlist[pos] = q; }
  }
  __syncthreads();
  int ovn = ovcnt;
  for (int e = 0; e < ovn; ++e) {      // block-cooperative full scan per overflow token
    int qq = ovlist[e];
    float Aq = Atok[qq];
    float bd = __builtin_inff(); int bk2 = 0;
    for (int it = 0; it < 64; ++it) {
      int k = it * 64 + q;
      float d2 = dist_np(k, qq, Aq);
      if (d2 < bd) { bd = d2; bk2 = k; }
    }
    if (j == 0) { bvD[q] = bd; bvK[q] = bk2; }
    __syncthreads();
    if (tid == 0) {
      float bb = bvD[0]; int kk2 = bvK[0];
      for (int r = 1; r < 64; ++r) {
        if (bvD[r] < bb || (bvD[r] == bb && bvK[r] < kk2)) { bb = bvD[r]; kk2 = bvK[r]; }
      }
      idxp[(t0 + qq) * 8 + m] = kk2;
    }
    __syncthreads();
  }
}

// ---------- out = q@Wo + bo (f32), plus per-block loss partials ----------
__global__ __launch_bounds__(256) void k_out(const float* __restrict__ cb,
                                             const float* __restrict__ Wo,
                                             const float* __restrict__ bo,
                                             const float* __restrict__ XH,
                                             const int* __restrict__ idxp,
                                             float* __restrict__ outp,
                                             double* __restrict__ lossp) {
  int bx = blockIdx.x;                 // grid 2048 = tt(256) * m(8)
  int m = bx & 7, tt = bx >> 3;
  int t0 = tt * 32;
  __shared__ float qT[256 * 32];       // [c][t] 32KB
  __shared__ float Wl[64 * 256];       // [c][d] 64KB
  __shared__ double red[256];
  int tid = threadIdx.x;
  {
    int tok = tid & 31, g = tid >> 5;
    int ix = idxp[(size_t)(t0 + tok) * 8 + m] & 4095;
    const float* qrow = cb + ((size_t)m * 4096 + ix) * 256;
#pragma unroll
    for (int i = 0; i < 8; ++i) {
      int c = (g * 8 + i) * 4;
      f32x4 v = *(const f32x4*)(qrow + c);
      qT[(c+0)*32+tok]=v[0]; qT[(c+1)*32+tok]=v[1]; qT[(c+2)*32+tok]=v[2]; qT[(c+3)*32+tok]=v[3];
    }
  }
  int tg = tid & 7, dg = tid >> 3;     // 8 tok-groups(4 tok) x 32 d-groups(8 d)
  float acc[4][8] = {};
  const float* wbase = Wo + (size_t)m * 65536;
  for (int c4 = 0; c4 < 4; ++c4) {
    __syncthreads();
#pragma unroll
    for (int i = 0; i < 16; ++i) {
      int f = tid + 256 * i;
      int cr = f >> 6, doff = (f & 63) * 4;
      *(f32x4*)&Wl[f * 4] = *(const f32x4*)(wbase + (size_t)(c4 * 64 + cr) * 256 + doff);
    }
    __syncthreads();
#pragma unroll 4
    for (int c = 0; c < 64; ++c) {
      f32x4 q4 = *(const f32x4*)&qT[(c4 * 64 + c) * 32 + tg * 4];
      f32x4 w0 = *(const f32x4*)&Wl[c * 256 + dg * 8];
      f32x4 w1 = *(const f32x4*)&Wl[c * 256 + dg * 8 + 4];
#pragma unroll
      for (int i = 0; i < 4; ++i) {
        acc[i][0]+=q4[i]*w0[0]; acc[i][1]+=q4[i]*w0[1]; acc[i][2]+=q4[i]*w0[2]; acc[i][3]+=q4[i]*w0[3];
        acc[i][4]+=q4[i]*w1[0]; acc[i][5]+=q4[i]*w1[1]; acc[i][6]+=q4[i]*w1[2]; acc[i][7]+=q4[i]*w1[3];
      }
    }
  }
#pragma unroll
  for (int i = 0; i < 4; ++i) {
    int t = t0 + tg * 4 + i;
    f32x4 lo, hi;
#pragma unroll
    for (int jj = 0; jj < 4; ++jj) {
      lo[jj] = acc[i][jj]     + bo[m * 256 + dg * 8 + jj];
      hi[jj] = acc[i][jj + 4] + bo[m * 256 + dg * 8 + 4 + jj];
    }
    float* dst = outp + (size_t)t * 2048 + m * 256 + dg * 8;
    *(f32x4*)(dst)     = lo;
    *(f32x4*)(dst + 4) = hi;
  }
  float lp = 0.0f;
  {
    int ltok = tid & 31, cg2 = tid >> 5;
    const float* xg = XH + (size_t)m * 2097152 + t0 + ltok;
    for (int c = cg2 * 32; c < cg2 * 32 + 32; ++c) {
      float qv = qT[c * 32 + ltok];
      float xv = xg[(size_t)c * 8192];
      float d = qv - xv; lp += d * d;
    }
  }
  red[tid] = (double)lp;
  __syncthreads();
  for (int off = 128; off; off >>= 1) { if (tid < off) red[tid] += red[tid + off]; __syncthreads(); }
  if (tid == 0) lossp[bx] = red[0];
}

// ---------- finalize loss (f32 at outp[16777216]) ----------
__global__ void k_final(const double* __restrict__ lossp, float* __restrict__ outp) {
  __shared__ double red[256];
  int tid = threadIdx.x;
  double s = 0.0;
  for (int i = 0; i < 8; ++i) s += lossp[tid + 256 * i];
  red[tid] = s; __syncthreads();
  for (int off = 128; off; off >>= 1) { if (tid < off) red[tid] += red[tid + off]; __syncthreads(); }
  if (tid == 0) outp[16777216] = (float)(1.25 * red[0] / 16777216.0);
}

// ---------- idx -> f32 ----------
__global__ void k_idxout(const int* __restrict__ idxp, float* __restrict__ outp) {
  int i = blockIdx.x * 256 + threadIdx.x;
  outp[16777217 + i] = (float)idxp[i];
}

extern "C" void kernel_launch(void* const* d_in, const int* in_sizes, int n_in,
                              void* d_out, int out_size, void* d_ws, size_t ws_size,
                              hipStream_t stream) {
  (void)in_sizes; (void)n_in; (void)out_size; (void)ws_size;
  const float* slots = (const float*)d_in[0];
  const float* Wp    = (const float*)d_in[1];
  const float* bp    = (const float*)d_in[2];
  const float* cb    = (const float*)d_in[3];
  const float* Wo    = (const float*)d_in[4];
  const float* bo    = (const float*)d_in[5];
  float* outp = (float*)d_out;
  char* ws = (char*)d_ws;
  double*         lossp = (double*)(ws + WS_LOSSP);
  unsigned int*   gumin = (unsigned int*)(ws + WS_UMIN);
  float*          B32   = (float*)(ws + WS_B32);
  int*            idxp  = (int*)(ws + WS_IDX);
  int*            cnts  = (int*)(ws + WS_CNT);
  unsigned short* lists = (unsigned short*)(ws + WS_LST);
  float*          XH    = (float*)(ws + WS_XH);
  unsigned short* CBb   = (unsigned short*)(ws + WS_CBT);

  hipMemsetAsync(gumin, 0xFF, 65536 * sizeof(unsigned int), stream);
  hipMemsetAsync(cnts,  0,    65536 * sizeof(int), stream);
  k_cbnormB<<<128,  256, 0, stream>>>(cb, B32);
  k_cbb    <<<2048, 256, 0, stream>>>(cb, CBb);
  k_xhat   <<<4096, 256, 0, stream>>>(slots, Wp, bp, XH);
  k_scanA  <<<512,  256, 0, stream>>>(XH, CBb, B32, gumin);
  k_scanB  <<<512,  256, 0, stream>>>(XH, CBb, B32, gumin, cnts, lists);
  k_select <<<1024, 256, 0, stream>>>(XH, cb, B32, cnts, lists, idxp);
  k_out    <<<2048, 256, 0, stream>>>(cb, Wo, bo, XH, idxp, outp, lossp);
  k_final  <<<1,    256, 0, stream>>>(lossp, outp);
  k_idxout <<<256,  256, 0, stream>>>(idxp, outp);
}

// Round 17
// 728.971 us; speedup vs baseline: 1.0882x; 1.0035x over previous
//
#include <hip/hip_runtime.h>
#include <hip/hip_bf16.h>

typedef float f32x4 __attribute__((ext_vector_type(4)));
typedef float f32x2 __attribute__((ext_vector_type(2)));
typedef short bf16x8 __attribute__((ext_vector_type(8)));

// ---- workspace layout (bytes) ----
static constexpr size_t WS_LOSSP = 0;         // double[2048]               -> 16384
static constexpr size_t WS_UMIN  = 16384;     // uint[65536] global min     -> 278528
static constexpr size_t WS_B32   = 294912;    // float[32768] np-exact B    -> 425984
static constexpr size_t WS_IDX   = 425984;    // int[65536]                 -> 688128
static constexpr size_t WS_CNT   = 688128;    // int[65536] cand counts     -> 950272
static constexpr size_t WS_LST   = 950272;    // ushort[65536*16] cand list -> 3047424
static constexpr size_t WS_XH    = 3145728;   // float[8*256*8192] 64MB     -> 70254592
static constexpr size_t WS_CBT   = 70254592;  // ushort bf16 frag-major     -> 87031808

#define DELTA 3.0e-4f

__device__ inline unsigned int fkey(float f) {
  unsigned int b = __float_as_uint(f); return (b & 0x80000000u) ? ~b : (b | 0x80000000u);
}
__device__ inline float funkey(unsigned int u) {
  unsigned int b = (u & 0x80000000u) ? (u ^ 0x80000000u) : ~u; return __uint_as_float(b);
}

// packed f32 ops: IEEE-exact per lane (identical results to scalar), half the instructions
__device__ inline f32x2 pk_mul(f32x2 a, f32x2 b) {
  f32x2 d;
  asm("v_pk_mul_f32 %0, %1, %2" : "=v"(d) : "v"(a), "v"(b));
  return d;
}
__device__ inline f32x2 pk_add(f32x2 a, f32x2 b) {
  f32x2 d;
  asm("v_pk_add_f32 %0, %1, %2" : "=v"(d) : "v"(a), "v"(b));
  return d;
}

// numpy pairwise_sum of 256 SQUARES, AVX512 width-16 emulation
__device__ inline float np_pw256sq(const float* p, int stride) {
#pragma clang fp contract(off)
  float h2[2];
#pragma unroll
  for (int hh = 0; hh < 2; ++hh) {
    const float* q = p + (size_t)(hh * 128) * stride;
    float V[16];
#pragma unroll
    for (int i = 0; i < 16; ++i) {
      float e[8];
#pragma unroll
      for (int j = 0; j < 8; ++j) { float x = q[(size_t)(j * 16 + i) * stride]; e[j] = x * x; }
      float t01 = e[0] + e[1], t23 = e[2] + e[3], t45 = e[4] + e[5], t67 = e[6] + e[7];
      float ta = t01 + t23, tb = t45 + t67;
      V[i] = ta + tb;
    }
    float u[8];
#pragma unroll
    for (int i = 0; i < 8; ++i) u[i] = V[i] + V[8 + i];
    float w[4];
#pragma unroll
    for (int i = 0; i < 4; ++i) w[i] = u[i] + u[4 + i];
    float wa = w[0] + w[2], wb = w[1] + w[3];
    h2[hh] = wa + wb;
  }
  return h2[0] + h2[1];
}

// ---------- np-exact codebook row norms ----------
__global__ __launch_bounds__(256) void k_cbnormB(const float* __restrict__ cb,
                                                 float* __restrict__ B32) {
  int row = blockIdx.x * 256 + threadIdx.x;      // grid 128 -> 32768 rows
  B32[row] = np_pw256sq(cb + (size_t)row * 256, 1);
}

// ---------- bf16 codebooks, FRAGMENT-MAJOR: [m][kt(256)][chunk p(512)] x 16B ----------
__global__ __launch_bounds__(256) void k_cbb(const float* __restrict__ cb,
                                             unsigned short* __restrict__ cbb) {
  int bx = blockIdx.x;                 // grid 2048 = m(8) * kt(256)
  int m = bx >> 8, kt = bx & 255;
  const float* src = cb + ((size_t)m * 4096 + kt * 16) * 256;
  unsigned short* dst = cbb + ((size_t)(m * 256 + kt)) * 4096;
  int tid = threadIdx.x;
#pragma unroll
  for (int h = 0; h < 2; ++h) {
    int p = tid + h * 256;
    int cs = p >> 6, lane = p & 63, row = lane & 15, grp = lane >> 4;
    const float* s = src + (size_t)row * 256 + grp * 8 + cs * 32;
    f32x4 v0 = *(const f32x4*)s;
    f32x4 v1 = *(const f32x4*)(s + 4);
    union { unsigned short us[8]; uint4 u; } o;
#pragma unroll
    for (int j = 0; j < 4; ++j) {
      __hip_bfloat16 h0 = __float2bfloat16(v0[j]);
      __hip_bfloat16 h1 = __float2bfloat16(v1[j]);
      o.us[j]     = *reinterpret_cast<unsigned short*>(&h0);
      o.us[4 + j] = *reinterpret_cast<unsigned short*>(&h1);
    }
    *(uint4*)(dst + (size_t)p * 8) = o.u;
  }
}

// ---------- x-hat: np.einsum-exact (sequential d, no FMA), pk-f32 ops, 16-d chunks ----------
__global__ __launch_bounds__(256) void k_xhat(const float* __restrict__ slots,
                                              const float* __restrict__ Wp,
                                              const float* __restrict__ bp,
                                              float* __restrict__ XH) {
#pragma clang fp contract(off)
  int bx = blockIdx.x;                 // grid 4096 = m(8) * tt(512)
  int m = bx & 7, tt = bx >> 3;
  int t0 = tt * 16;
  __shared__ float Ls[16 * 260];       // [tok][d], stride 260 -> 2-way-free reads, 16B rows
  __shared__ float Wt[16 * 264];       // [d-chunk of 16][256 ch + pad]  (16.9KB)
  int tid = threadIdx.x;
  {                                    // stage 16 tokens x 256 d (1024 f32x4)
#pragma unroll
    for (int i = 0; i < 4; ++i) {
      int f = tid + 256 * i;
      int r = f >> 6, seg = f & 63;
      *(f32x4*)&Ls[r * 260 + seg * 4] =
          *(const f32x4*)(slots + (size_t)(t0 + r) * 2048 + m * 256 + seg * 4);
    }
  }
  int tl = tid & 15, g = tid >> 4;     // 16 tokens x 16 ch-groups (16 ch each)
  const float* lsrow = &Ls[tl * 260];
  const f32x4* wglob = (const f32x4*)(Wp + (size_t)m * 65536);
  f32x4 preg[4];
#pragma unroll
  for (int i = 0; i < 4; ++i) preg[i] = wglob[tid + 256 * i];   // chunk 0 (16 d x 256 ch)

  f32x2 acc[8];
#pragma unroll
  for (int i = 0; i < 8; ++i) acc[i] = f32x2{0.f, 0.f};

  for (int chunk = 0; chunk < 16; ++chunk) {
    __syncthreads();                   // prior chunk reads done (covers Ls staging, iter 0)
    {                                  // regs -> LDS (2-way free)
      f32x4* wt4 = (f32x4*)Wt;
#pragma unroll
      for (int i = 0; i < 4; ++i) {
        int q = tid + 256 * i;
        wt4[(q >> 6) * 66 + (q & 63)] = preg[i];
      }
    }
    __syncthreads();
    if (chunk + 1 < 16) {              // prefetch next chunk (hidden under compute)
      const f32x4* src = wglob + (chunk + 1) * 1024;
#pragma unroll
      for (int i = 0; i < 4; ++i) preg[i] = src[tid + 256 * i];
    }
    const float* xs = lsrow + chunk * 16;
#pragma unroll 4
    for (int d = 0; d < 16; ++d) {
      float x = xs[d];
      f32x2 x2 = {x, x};
      const f32x4* wrow = (const f32x4*)&Wt[d * 264 + g * 16];
#pragma unroll
      for (int cq = 0; cq < 4; ++cq) {
        f32x4 wv = wrow[cq];
        f32x2 wlo = {wv[0], wv[1]};
        f32x2 whi = {wv[2], wv[3]};
        acc[cq * 2]     = pk_add(acc[cq * 2],     pk_mul(x2, wlo));   // strict d-order
        acc[cq * 2 + 1] = pk_add(acc[cq * 2 + 1], pk_mul(x2, whi));
      }
    }
  }
  int ch0 = g * 16;
  const float* bpb = bp + m * 256 + ch0;
  float* xgbase = XH + (size_t)m * 2097152 + t0 + tl;
#pragma unroll
  for (int i = 0; i < 8; ++i) {
    float v0 = acc[i][0] + bpb[i * 2];
    float v1 = acc[i][1] + bpb[i * 2 + 1];
    xgbase[(size_t)(ch0 + i * 2) * 8192]     = v0;
    xgbase[(size_t)(ch0 + i * 2 + 1) * 8192] = v1;
  }
}

// ---------- scan pass A: MFMA min, 64 tok/wave, 3-deep counted-vmcnt pipeline ----------
// grid 512 = tt(32) * ks(2) * m(8); block = 4 waves x 64 toks = 256 tokens, 128 k-tiles
__global__ __launch_bounds__(256, 2) void k_scanA(const float* __restrict__ XH,
                                                  const unsigned short* __restrict__ CBb,
                                                  const float* __restrict__ B32,
                                                  unsigned int* __restrict__ gumin) {
  int bx = blockIdx.x;
  int m = bx & 7, ks = (bx >> 3) & 1, tt = bx >> 4;
  int t0 = tt * 256, kt0 = ks * 128;
  __shared__ unsigned short Bt[3][2 * 4096];   // 3 bufs x 16KB (48KB)
  __shared__ unsigned int umin[256];
  int tid = threadIdx.x;
  umin[tid] = 0xFFFFFFFFu;
  int w = tid >> 6, l = tid & 63;
  int row = l & 15, grp = l >> 4;
  int tbase = w * 64;
  const float FINF = __builtin_inff();

  bf16x8 afrag[4][8];
  {
    const float* xbase = XH + (size_t)m * 2097152;
#pragma unroll
    for (int a = 0; a < 4; ++a)
#pragma unroll
      for (int cs = 0; cs < 8; ++cs) {
        union { short s[8]; bf16x8 v; } u;
#pragma unroll
        for (int j = 0; j < 8; ++j) {
          int c = cs * 32 + grp * 8 + j;
          float x = xbase[(size_t)c * 8192 + t0 + tbase + a * 16 + row];
          __hip_bfloat16 h = __float2bfloat16(x);
          u.s[j] = *reinterpret_cast<short*>(&h);
        }
        afrag[a][cs] = u.v;
      }
  }

  const uint4* cbsrc = (const uint4*)(CBb + (size_t)m * 1048576);
  const float* bvbase = B32 + m * 4096;
  auto stage = [&](int g, int b) {     // async: group g (16KB) -> Bt[b]; 4 loads/wave
    const uint4* s = cbsrc + (size_t)(kt0 + 2 * g) * 512;
    uint4* db = (uint4*)Bt[b];
#pragma unroll
    for (int h = 0; h < 4; ++h) {
      int c0 = h * 256 + w * 64;       // wave-uniform 1KB window; lane offset = l*16B (HW)
      __builtin_amdgcn_global_load_lds(
          (const __attribute__((address_space(1))) void*)(s + c0 + l),
          (__attribute__((address_space(3))) void*)(db + c0),
          16, 0, 0);
    }
  };

  float rmin[16];
#pragma unroll
  for (int sl = 0; sl < 16; ++sl) rmin[sl] = FINF;
  stage(0, 0); stage(1, 1);
  asm volatile("s_waitcnt vmcnt(4)" ::: "memory");   // group 0 resident
  __builtin_amdgcn_s_barrier();                      // also covers umin init
  for (int p = 0; p < 64; ++p) {
    int b = p % 3;
    if (p + 2 < 64) stage(p + 2, (p + 2) % 3);       // buf free since phase-p barrier
#pragma unroll
    for (int t = 0; t < 2; ++t) {
      int kt = kt0 + 2 * p + t;
      float Bv = bvbase[kt * 16 + row];
      f32x4 acc[4];
#pragma unroll
      for (int a = 0; a < 4; ++a) acc[a] = f32x4{0.f,0.f,0.f,0.f};
#pragma unroll
      for (int cs = 0; cs < 8; ++cs) {
        bf16x8 bf = *(const bf16x8*)&Bt[b][t * 4096 + cs * 512 + l * 8];
#pragma unroll
        for (int a = 0; a < 4; ++a)
          acc[a] = __builtin_amdgcn_mfma_f32_16x16x32_bf16(afrag[a][cs], bf, acc[a], 0, 0, 0);
      }
#pragma unroll
      for (int a = 0; a < 4; ++a)
#pragma unroll
        for (int r = 0; r < 4; ++r)
          rmin[a * 4 + r] = fminf(rmin[a * 4 + r], fmaf(-2.0f, acc[a][r], Bv));
    }
    if (p < 62) {                      // counted: group p+1 landed, p+2 may still fly
      asm volatile("s_waitcnt vmcnt(4)" ::: "memory");
      __builtin_amdgcn_s_barrier();
    } else if (p == 62) {
      asm volatile("s_waitcnt vmcnt(0)" ::: "memory");
      __builtin_amdgcn_s_barrier();
    }
  }
#pragma unroll
  for (int a = 0; a < 4; ++a)
#pragma unroll
    for (int r = 0; r < 4; ++r)
      atomicMin(&umin[tbase + a * 16 + grp * 4 + r], fkey(rmin[a * 4 + r]));
  __syncthreads();
  atomicMin(&gumin[(size_t)(t0 + tid) * 8 + m], umin[tid]);
}

// ---------- scan pass B: recompute vs FINAL threshold, 64 tok/wave, counted-vmcnt ----------
__global__ __launch_bounds__(256, 2) void k_scanB(const float* __restrict__ XH,
                                                  const unsigned short* __restrict__ CBb,
                                                  const float* __restrict__ B32,
                                                  const unsigned int* __restrict__ gumin,
                                                  int* __restrict__ cnts,
                                                  unsigned short* __restrict__ lists) {
  int bx = blockIdx.x;
  int m = bx & 7, ks = (bx >> 3) & 1, tt = bx >> 4;
  int t0 = tt * 256, kt0 = ks * 128;
  __shared__ unsigned short Bt[3][2 * 4096];   // 48KB
  __shared__ int lcnt[256];
  __shared__ unsigned short llist[256][16];
  int tid = threadIdx.x;
  lcnt[tid] = 0;
  int w = tid >> 6, l = tid & 63;
  int row = l & 15, grp = l >> 4;
  int tbase = w * 64;

  bf16x8 afrag[4][8];
  {
    const float* xbase = XH + (size_t)m * 2097152;
#pragma unroll
    for (int a = 0; a < 4; ++a)
#pragma unroll
      for (int cs = 0; cs < 8; ++cs) {
        union { short s[8]; bf16x8 v; } u;
#pragma unroll
        for (int j = 0; j < 8; ++j) {
          int c = cs * 32 + grp * 8 + j;
          float x = xbase[(size_t)c * 8192 + t0 + tbase + a * 16 + row];
          __hip_bfloat16 h = __float2bfloat16(x);
          u.s[j] = *reinterpret_cast<short*>(&h);
        }
        afrag[a][cs] = u.v;
      }
  }
  float thr[16];
#pragma unroll
  for (int a = 0; a < 4; ++a)
#pragma unroll
    for (int r = 0; r < 4; ++r) {
      int tok = t0 + tbase + a * 16 + grp * 4 + r;
      thr[a * 4 + r] = funkey(gumin[(size_t)tok * 8 + m]) + DELTA;   // final (post-scanA)
    }

  const uint4* cbsrc = (const uint4*)(CBb + (size_t)m * 1048576);
  const float* bvbase = B32 + m * 4096;
  auto stage = [&](int g, int b) {
    const uint4* s = cbsrc + (size_t)(kt0 + 2 * g) * 512;
    uint4* db = (uint4*)Bt[b];
#pragma unroll
    for (int h = 0; h < 4; ++h) {
      int c0 = h * 256 + w * 64;
      __builtin_amdgcn_global_load_lds(
          (const __attribute__((address_space(1))) void*)(s + c0 + l),
          (__attribute__((address_space(3))) void*)(db + c0),
          16, 0, 0);
    }
  };

  stage(0, 0); stage(1, 1);
  asm volatile("s_waitcnt vmcnt(4)" ::: "memory");
  __builtin_amdgcn_s_barrier();                      // also covers lcnt init
  for (int p = 0; p < 64; ++p) {
    int b = p % 3;
    if (p + 2 < 64) stage(p + 2, (p + 2) % 3);
#pragma unroll
    for (int t = 0; t < 2; ++t) {
      int kt = kt0 + 2 * p + t;
      float Bv = bvbase[kt * 16 + row];
      f32x4 acc[4];
#pragma unroll
      for (int a = 0; a < 4; ++a) acc[a] = f32x4{0.f,0.f,0.f,0.f};
#pragma unroll
      for (int cs = 0; cs < 8; ++cs) {
        bf16x8 bf = *(const bf16x8*)&Bt[b][t * 4096 + cs * 512 + l * 8];
#pragma unroll
        for (int a = 0; a < 4; ++a)
          acc[a] = __builtin_amdgcn_mfma_f32_16x16x32_bf16(afrag[a][cs], bf, acc[a], 0, 0, 0);
      }
      int k = (kt << 4) + row;
#pragma unroll
      for (int a = 0; a < 4; ++a)
#pragma unroll
        for (int r = 0; r < 4; ++r) {
          float s = fmaf(-2.0f, acc[a][r], Bv);
          if (s <= thr[a * 4 + r]) {
            int tok = tbase + a * 16 + grp * 4 + r;
            int pos = atomicAdd(&lcnt[tok], 1);
            if (pos < 16) llist[tok][pos] = (unsigned short)k;
          }
        }
    }
    if (p < 62) {
      asm volatile("s_waitcnt vmcnt(4)" ::: "memory");
      __builtin_amdgcn_s_barrier();
    } else if (p == 62) {
      asm volatile("s_waitcnt vmcnt(0)" ::: "memory");
      __builtin_amdgcn_s_barrier();
    }
  }
  __syncthreads();                     // all inserts visible before flush
  // flush: accumulate into global cnts/lists (two ks-blocks share each token)
  {
    int n = lcnt[tid];
    if (n > 0) {
      size_t t8m = (size_t)(t0 + tid) * 8 + m;
      int base = atomicAdd(&cnts[t8m], n);
      int nc = n < 16 ? n : 16;
      for (int i = 0; i < nc && base + i < 16; ++i)
        lists[t8m * 16 + base + i] = llist[tid][i];
    }
  }
}

// ---------- np-f32-exact final selection among candidates ----------
__global__ __launch_bounds__(256) void k_select(const float* __restrict__ XH,
                                                const float* __restrict__ cb,
                                                const float* __restrict__ B32,
                                                const int* __restrict__ cnts,
                                                const unsigned short* __restrict__ lists,
                                                int* __restrict__ idxp) {
#pragma clang fp contract(off)
  int bx = blockIdx.x;                 // grid 1024 = tt(128) * m(8)
  int m = bx & 7, tt = bx >> 3;
  int t0 = tt * 64;
  __shared__ float XT2[256 * 65];      // padded [c][t]
  __shared__ float Atok[64];
  __shared__ int ovlist[64];
  __shared__ int ovcnt;
  __shared__ float bvD[64];
  __shared__ int bvK[64];
  int tid = threadIdx.x;
  const float* xsrc = XH + (size_t)m * 2097152;
#pragma unroll
  for (int i = 0; i < 16; ++i) {
    int f = tid + 256 * i;
    int c = f >> 4, to = (f & 15) * 4;
    f32x4 v = *(const f32x4*)(xsrc + (size_t)c * 8192 + t0 + to);
    XT2[c*65+to+0]=v[0]; XT2[c*65+to+1]=v[1]; XT2[c*65+to+2]=v[2]; XT2[c*65+to+3]=v[3];
  }
  if (tid == 0) ovcnt = 0;
  __syncthreads();
  if (tid < 64) Atok[tid] = np_pw256sq(&XT2[tid], 65);   // np.sum(x*x) emulation
  __syncthreads();
  int q = tid >> 2, j = tid & 3;       // 64 quads (token t0+q) x 4 SSE lanes
  const float* cbm = cb + (size_t)m * 1048576;

  auto dist_np = [&](int k, int qq, float A) -> float {
#pragma clang fp contract(off)
    const float* row = cbm + (size_t)k * 256;
    float s = 0.0f;
    for (int i8 = 0; i8 < 256; i8 += 8) {
      float p0 = XT2[(i8 + j) * 65 + qq] * row[i8 + j];
      s = s + p0;
      float p1 = XT2[(i8 + 4 + j) * 65 + qq] * row[i8 + 4 + j];
      s = s + p1;
    }
    float o  = __shfl_xor(s, 1, 64);
    float ts = s + o;
    float o2 = __shfl_xor(ts, 2, 64);
    float red = ts + o2;               // (s0+s1)+(s2+s3)
    float T1 = A + B32[m * 4096 + k];  // fl(A + Bk)
    return T1 - 2.0f * red;            // fl(T1 - fl(2E))
  };

  int t8m = (t0 + q) * 8 + m;
  int n = cnts[t8m];
  float A = Atok[q];
  if (n <= 16) {
    float best = __builtin_inff();
    int bk = 0;
    for (int ci = 0; ci < n; ++ci) {
      int k = (int)lists[(size_t)t8m * 16 + ci] & 4095;
      float d2 = dist_np(k, q, A);
      if (d2 < best || (d2 == best && k < bk)) { best = d2; bk = k; }
    }
    if (j == 0) idxp[t8m] = bk;
  } else {
    if (j == 0) { int pos = atomicAdd(&ovcnt, 1); ovlist[pos] = q; }
  }
  __syncthreads();
  int ovn = ovcnt;
  for (int e = 0; e < ovn; ++e) {      // block-cooperative full scan per overflow token
    int qq = ovlist[e];
    float Aq = Atok[qq];
    float bd = __builtin_inff(); int bk2 = 0;
    for (int it = 0; it < 64; ++it) {
      int k = it * 64 + q;
      float d2 = dist_np(k, qq, Aq);
      if (d2 < bd) { bd = d2; bk2 = k; }
    }
    if (j == 0) { bvD[q] = bd; bvK[q] = bk2; }
    __syncthreads();
    if (tid == 0) {
      float bb = bvD[0]; int kk2 = bvK[0];
      for (int r = 1; r < 64; ++r) {
        if (bvD[r] < bb || (bvD[r] == bb && bvK[r] < kk2)) { bb = bvD[r]; kk2 = bvK[r]; }
      }
      idxp[(t0 + qq) * 8 + m] = kk2;
    }
    __syncthreads();
  }
}

// ---------- out = q@Wo + bo (f32), plus per-block loss partials ----------
__global__ __launch_bounds__(256) void k_out(const float* __restrict__ cb,
                                             const float* __restrict__ Wo,
                                             const float* __restrict__ bo,
                                             const float* __restrict__ XH,
                                             const int* __restrict__ idxp,
                                             float* __restrict__ outp,
                                             double* __restrict__ lossp) {
  int bx = blockIdx.x;                 // grid 2048 = tt(256) * m(8)
  int m = bx & 7, tt = bx >> 3;
  int t0 = tt * 32;
  __shared__ float qT[256 * 32];       // [c][t] 32KB
  __shared__ float Wl[64 * 256];       // [c][d] 64KB
  __shared__ double red[256];
  int tid = threadIdx.x;
  {
    int tok = tid & 31, g = tid >> 5;
    int ix = idxp[(size_t)(t0 + tok) * 8 + m] & 4095;
    const float* qrow = cb + ((size_t)m * 4096 + ix) * 256;
#pragma unroll
    for (int i = 0; i < 8; ++i) {
      int c = (g * 8 + i) * 4;
      f32x4 v = *(const f32x4*)(qrow + c);
      qT[(c+0)*32+tok]=v[0]; qT[(c+1)*32+tok]=v[1]; qT[(c+2)*32+tok]=v[2]; qT[(c+3)*32+tok]=v[3];
    }
  }
  int tg = tid & 7, dg = tid >> 3;     // 8 tok-groups(4 tok) x 32 d-groups(8 d)
  float acc[4][8] = {};
  const float* wbase = Wo + (size_t)m * 65536;
  for (int c4 = 0; c4 < 4; ++c4) {
    __syncthreads();
#pragma unroll
    for (int i = 0; i < 16; ++i) {
      int f = tid + 256 * i;
      int cr = f >> 6, doff = (f & 63) * 4;
      *(f32x4*)&Wl[f * 4] = *(const f32x4*)(wbase + (size_t)(c4 * 64 + cr) * 256 + doff);
    }
    __syncthreads();
#pragma unroll 4
    for (int c = 0; c < 64; ++c) {
      f32x4 q4 = *(const f32x4*)&qT[(c4 * 64 + c) * 32 + tg * 4];
      f32x4 w0 = *(const f32x4*)&Wl[c * 256 + dg * 8];
      f32x4 w1 = *(const f32x4*)&Wl[c * 256 + dg * 8 + 4];
#pragma unroll
      for (int i = 0; i < 4; ++i) {
        acc[i][0]+=q4[i]*w0[0]; acc[i][1]+=q4[i]*w0[1]; acc[i][2]+=q4[i]*w0[2]; acc[i][3]+=q4[i]*w0[3];
        acc[i][4]+=q4[i]*w1[0]; acc[i][5]+=q4[i]*w1[1]; acc[i][6]+=q4[i]*w1[2]; acc[i][7]+=q4[i]*w1[3];
      }
    }
  }
#pragma unroll
  for (int i = 0; i < 4; ++i) {
    int t = t0 + tg * 4 + i;
    f32x4 lo, hi;
#pragma unroll
    for (int jj = 0; jj < 4; ++jj) {
      lo[jj] = acc[i][jj]     + bo[m * 256 + dg * 8 + jj];
      hi[jj] = acc[i][jj + 4] + bo[m * 256 + dg * 8 + 4 + jj];
    }
    float* dst = outp + (size_t)t * 2048 + m * 256 + dg * 8;
    *(f32x4*)(dst)     = lo;
    *(f32x4*)(dst + 4) = hi;
  }
  float lp = 0.0f;
  {
    int ltok = tid & 31, cg2 = tid >> 5;
    const float* xg = XH + (size_t)m * 2097152 + t0 + ltok;
    for (int c = cg2 * 32; c < cg2 * 32 + 32; ++c) {
      float qv = qT[c * 32 + ltok];
      float xv = xg[(size_t)c * 8192];
      float d = qv - xv; lp += d * d;
    }
  }
  red[tid] = (double)lp;
  __syncthreads();
  for (int off = 128; off; off >>= 1) { if (tid < off) red[tid] += red[tid + off]; __syncthreads(); }
  if (tid == 0) lossp[bx] = red[0];
}

// ---------- finalize loss (f32 at outp[16777216]) ----------
__global__ void k_final(const double* __restrict__ lossp, float* __restrict__ outp) {
  __shared__ double red[256];
  int tid = threadIdx.x;
  double s = 0.0;
  for (int i = 0; i < 8; ++i) s += lossp[tid + 256 * i];
  red[tid] = s; __syncthreads();
  for (int off = 128; off; off >>= 1) { if (tid < off) red[tid] += red[tid + off]; __syncthreads(); }
  if (tid == 0) outp[16777216] = (float)(1.25 * red[0] / 16777216.0);
}

// ---------- idx -> f32 ----------
__global__ void k_idxout(const int* __restrict__ idxp, float* __restrict__ outp) {
  int i = blockIdx.x * 256 + threadIdx.x;
  outp[16777217 + i] = (float)idxp[i];
}

extern "C" void kernel_launch(void* const* d_in, const int* in_sizes, int n_in,
                              void* d_out, int out_size, void* d_ws, size_t ws_size,
                              hipStream_t stream) {
  (void)in_sizes; (void)n_in; (void)out_size; (void)ws_size;
  const float* slots = (const float*)d_in[0];
  const float* Wp    = (const float*)d_in[1];
  const float* bp    = (const float*)d_in[2];
  const float* cb    = (const float*)d_in[3];
  const float* Wo    = (const float*)d_in[4];
  const float* bo    = (const float*)d_in[5];
  float* outp = (float*)d_out;
  char* ws = (char*)d_ws;
  double*         lossp = (double*)(ws + WS_LOSSP);
  unsigned int*   gumin = (unsigned int*)(ws + WS_UMIN);
  float*          B32   = (float*)(ws + WS_B32);
  int*            idxp  = (int*)(ws + WS_IDX);
  int*            cnts  = (int*)(ws + WS_CNT);
  unsigned short* lists = (unsigned short*)(ws + WS_LST);
  float*          XH    = (float*)(ws + WS_XH);
  unsigned short* CBb   = (unsigned short*)(ws + WS_CBT);

  hipMemsetAsync(gumin, 0xFF, 65536 * sizeof(unsigned int), stream);
  hipMemsetAsync(cnts,  0,    65536 * sizeof(int), stream);
  k_cbnormB<<<128,  256, 0, stream>>>(cb, B32);
  k_cbb    <<<2048, 256, 0, stream>>>(cb, CBb);
  k_xhat   <<<4096, 256, 0, stream>>>(slots, Wp, bp, XH);
  k_scanA  <<<512,  256, 0, stream>>>(XH, CBb, B32, gumin);
  k_scanB  <<<512,  256, 0, stream>>>(XH, CBb, B32, gumin, cnts, lists);
  k_select <<<1024, 256, 0, stream>>>(XH, cb, B32, cnts, lists, idxp);
  k_out    <<<2048, 256, 0, stream>>>(cb, Wo, bo, XH, idxp, outp, lossp);
  k_final  <<<1,    256, 0, stream>>>(lossp, outp);
  k_idxout <<<256,  256, 0, stream>>>(idxp, outp);
}

// Round 18
// 595.391 us; speedup vs baseline: 1.3324x; 1.2244x over previous
//
#include <hip/hip_runtime.h>
#include <hip/hip_bf16.h>

typedef float f32x4 __attribute__((ext_vector_type(4)));
typedef float f32x2 __attribute__((ext_vector_type(2)));
typedef short bf16x8 __attribute__((ext_vector_type(8)));

// ---- workspace layout (bytes) ----
static constexpr size_t WS_LOSSP = 0;         // double[2048]               -> 16384
static constexpr size_t WS_UMIN  = 16384;     // uint[65536] global min     -> 278528
static constexpr size_t WS_B32   = 294912;    // float[32768] np-exact B    -> 425984
static constexpr size_t WS_IDX   = 425984;    // int[65536]                 -> 688128
static constexpr size_t WS_CNT   = 688128;    // int[65536] cand counts     -> 950272
static constexpr size_t WS_LST   = 950272;    // ushort[65536*16] cand list -> 3047424
static constexpr size_t WS_XH    = 3145728;   // float[8*256*8192] 64MB     -> 70254592
static constexpr size_t WS_CBT   = 70254592;  // ushort bf16 frag-major     -> 87031808
static constexpr size_t WS_WOT   = 87031808;  // ushort bf16 WoT frag-major -> 88080384

#define DELTA 3.0e-4f

__device__ inline unsigned int fkey(float f) {
  unsigned int b = __float_as_uint(f); return (b & 0x80000000u) ? ~b : (b | 0x80000000u);
}
__device__ inline float funkey(unsigned int u) {
  unsigned int b = (u & 0x80000000u) ? (u ^ 0x80000000u) : ~u; return __uint_as_float(b);
}

// packed f32 ops: IEEE-exact per lane (identical results to scalar), half the instructions
__device__ inline f32x2 pk_mul(f32x2 a, f32x2 b) {
  f32x2 d;
  asm("v_pk_mul_f32 %0, %1, %2" : "=v"(d) : "v"(a), "v"(b));
  return d;
}
__device__ inline f32x2 pk_add(f32x2 a, f32x2 b) {
  f32x2 d;
  asm("v_pk_add_f32 %0, %1, %2" : "=v"(d) : "v"(a), "v"(b));
  return d;
}

// numpy pairwise_sum of 256 SQUARES, AVX512 width-16 emulation
__device__ inline float np_pw256sq(const float* p, int stride) {
#pragma clang fp contract(off)
  float h2[2];
#pragma unroll
  for (int hh = 0; hh < 2; ++hh) {
    const float* q = p + (size_t)(hh * 128) * stride;
    float V[16];
#pragma unroll
    for (int i = 0; i < 16; ++i) {
      float e[8];
#pragma unroll
      for (int j = 0; j < 8; ++j) { float x = q[(size_t)(j * 16 + i) * stride]; e[j] = x * x; }
      float t01 = e[0] + e[1], t23 = e[2] + e[3], t45 = e[4] + e[5], t67 = e[6] + e[7];
      float ta = t01 + t23, tb = t45 + t67;
      V[i] = ta + tb;
    }
    float u[8];
#pragma unroll
    for (int i = 0; i < 8; ++i) u[i] = V[i] + V[8 + i];
    float w[4];
#pragma unroll
    for (int i = 0; i < 4; ++i) w[i] = u[i] + u[4 + i];
    float wa = w[0] + w[2], wb = w[1] + w[3];
    h2[hh] = wa + wb;
  }
  return h2[0] + h2[1];
}

// ---------- np-exact codebook row norms ----------
__global__ __launch_bounds__(256) void k_cbnormB(const float* __restrict__ cb,
                                                 float* __restrict__ B32) {
  int row = blockIdx.x * 256 + threadIdx.x;      // grid 128 -> 32768 rows
  B32[row] = np_pw256sq(cb + (size_t)row * 256, 1);
}

// ---------- bf16 codebooks, FRAGMENT-MAJOR: [m][kt(256)][chunk p(512)] x 16B ----------
__global__ __launch_bounds__(256) void k_cbb(const float* __restrict__ cb,
                                             unsigned short* __restrict__ cbb) {
  int bx = blockIdx.x;                 // grid 2048 = m(8) * kt(256)
  int m = bx >> 8, kt = bx & 255;
  const float* src = cb + ((size_t)m * 4096 + kt * 16) * 256;
  unsigned short* dst = cbb + ((size_t)(m * 256 + kt)) * 4096;
  int tid = threadIdx.x;
#pragma unroll
  for (int h = 0; h < 2; ++h) {
    int p = tid + h * 256;
    int cs = p >> 6, lane = p & 63, row = lane & 15, grp = lane >> 4;
    const float* s = src + (size_t)row * 256 + grp * 8 + cs * 32;
    f32x4 v0 = *(const f32x4*)s;
    f32x4 v1 = *(const f32x4*)(s + 4);
    union { unsigned short us[8]; uint4 u; } o;
#pragma unroll
    for (int j = 0; j < 4; ++j) {
      __hip_bfloat16 h0 = __float2bfloat16(v0[j]);
      __hip_bfloat16 h1 = __float2bfloat16(v1[j]);
      o.us[j]     = *reinterpret_cast<unsigned short*>(&h0);
      o.us[4 + j] = *reinterpret_cast<unsigned short*>(&h1);
    }
    *(uint4*)(dst + (size_t)p * 8) = o.u;
  }
}

// ---------- WoT bf16 frag-major: [m][dt(16)][chunk p(512)] x 16B ----------
// chunk p: cs=p>>6, lane=p&63, row=lane&15, grp=lane>>4
// contents j=0..7: Wo[m][c = cs*32+grp*8+j][d = dt*16+row]
__global__ __launch_bounds__(256) void k_wot(const float* __restrict__ Wo,
                                             unsigned short* __restrict__ wot) {
  int bx = blockIdx.x;                 // grid 128 = m(8) * dt(16)
  int m = bx >> 4, dt = bx & 15;
  const float* src = Wo + (size_t)m * 65536 + dt * 16;   // [c][d] d-contig
  unsigned short* dst = wot + ((size_t)(m * 16 + dt)) * 4096;
  int tid = threadIdx.x;
#pragma unroll
  for (int h = 0; h < 2; ++h) {
    int p = tid + h * 256;
    int cs = p >> 6, lane = p & 63, row = lane & 15, grp = lane >> 4;
    union { unsigned short us[8]; uint4 u; } o;
#pragma unroll
    for (int j = 0; j < 8; ++j) {
      float v = src[(size_t)(cs * 32 + grp * 8 + j) * 256 + row];
      __hip_bfloat16 hb = __float2bfloat16(v);
      o.us[j] = *reinterpret_cast<unsigned short*>(&hb);
    }
    *(uint4*)(dst + (size_t)p * 8) = o.u;
  }
}

// ---------- x-hat: np.einsum-exact (sequential d, no FMA), pk-f32 ops, 16-d chunks ----------
__global__ __launch_bounds__(256) void k_xhat(const float* __restrict__ slots,
                                              const float* __restrict__ Wp,
                                              const float* __restrict__ bp,
                                              float* __restrict__ XH) {
#pragma clang fp contract(off)
  int bx = blockIdx.x;                 // grid 4096 = m(8) * tt(512)
  int m = bx & 7, tt = bx >> 3;
  int t0 = tt * 16;
  __shared__ float Ls[16 * 260];       // [tok][d], stride 260 -> 2-way-free reads, 16B rows
  __shared__ float Wt[16 * 264];       // [d-chunk of 16][256 ch + pad]  (16.9KB)
  int tid = threadIdx.x;
  {                                    // stage 16 tokens x 256 d (1024 f32x4)
#pragma unroll
    for (int i = 0; i < 4; ++i) {
      int f = tid + 256 * i;
      int r = f >> 6, seg = f & 63;
      *(f32x4*)&Ls[r * 260 + seg * 4] =
          *(const f32x4*)(slots + (size_t)(t0 + r) * 2048 + m * 256 + seg * 4);
    }
  }
  int tl = tid & 15, g = tid >> 4;     // 16 tokens x 16 ch-groups (16 ch each)
  const float* lsrow = &Ls[tl * 260];
  const f32x4* wglob = (const f32x4*)(Wp + (size_t)m * 65536);
  f32x4 preg[4];
#pragma unroll
  for (int i = 0; i < 4; ++i) preg[i] = wglob[tid + 256 * i];   // chunk 0 (16 d x 256 ch)

  f32x2 acc[8];
#pragma unroll
  for (int i = 0; i < 8; ++i) acc[i] = f32x2{0.f, 0.f};

  for (int chunk = 0; chunk < 16; ++chunk) {
    __syncthreads();                   // prior chunk reads done (covers Ls staging, iter 0)
    {                                  // regs -> LDS
      f32x4* wt4 = (f32x4*)Wt;
#pragma unroll
      for (int i = 0; i < 4; ++i) {
        int q = tid + 256 * i;
        wt4[(q >> 6) * 66 + (q & 63)] = preg[i];
      }
    }
    __syncthreads();
    if (chunk + 1 < 16) {              // prefetch next chunk (hidden under compute)
      const f32x4* src = wglob + (chunk + 1) * 1024;
#pragma unroll
      for (int i = 0; i < 4; ++i) preg[i] = src[tid + 256 * i];
    }
    const float* xs = lsrow + chunk * 16;
#pragma unroll 4
    for (int d = 0; d < 16; ++d) {
      float x = xs[d];
      f32x2 x2 = {x, x};
      const f32x4* wrow = (const f32x4*)&Wt[d * 264 + g * 16];
#pragma unroll
      for (int cq = 0; cq < 4; ++cq) {
        f32x4 wv = wrow[cq];
        f32x2 wlo = {wv[0], wv[1]};
        f32x2 whi = {wv[2], wv[3]};
        acc[cq * 2]     = pk_add(acc[cq * 2],     pk_mul(x2, wlo));   // strict d-order
        acc[cq * 2 + 1] = pk_add(acc[cq * 2 + 1], pk_mul(x2, whi));
      }
    }
  }
  int ch0 = g * 16;
  const float* bpb = bp + m * 256 + ch0;
  float* xgbase = XH + (size_t)m * 2097152 + t0 + tl;
#pragma unroll
  for (int i = 0; i < 8; ++i) {
    float v0 = acc[i][0] + bpb[i * 2];
    float v1 = acc[i][1] + bpb[i * 2 + 1];
    xgbase[(size_t)(ch0 + i * 2) * 8192]     = v0;
    xgbase[(size_t)(ch0 + i * 2 + 1) * 8192] = v1;
  }
}

// ---------- scan pass A: MFMA min, 64 tok/wave, 3-deep counted-vmcnt pipeline ----------
// grid 512 = tt(32) * ks(2) * m(8); block = 4 waves x 64 toks = 256 tokens, 128 k-tiles
__global__ __launch_bounds__(256, 2) void k_scanA(const float* __restrict__ XH,
                                                  const unsigned short* __restrict__ CBb,
                                                  const float* __restrict__ B32,
                                                  unsigned int* __restrict__ gumin) {
  int bx = blockIdx.x;
  int m = bx & 7, ks = (bx >> 3) & 1, tt = bx >> 4;
  int t0 = tt * 256, kt0 = ks * 128;
  __shared__ unsigned short Bt[3][2 * 4096];   // 3 bufs x 16KB (48KB)
  __shared__ unsigned int umin[256];
  int tid = threadIdx.x;
  umin[tid] = 0xFFFFFFFFu;
  int w = tid >> 6, l = tid & 63;
  int row = l & 15, grp = l >> 4;
  int tbase = w * 64;
  const float FINF = __builtin_inff();

  bf16x8 afrag[4][8];
  {
    const float* xbase = XH + (size_t)m * 2097152;
#pragma unroll
    for (int a = 0; a < 4; ++a)
#pragma unroll
      for (int cs = 0; cs < 8; ++cs) {
        union { short s[8]; bf16x8 v; } u;
#pragma unroll
        for (int j = 0; j < 8; ++j) {
          int c = cs * 32 + grp * 8 + j;
          float x = xbase[(size_t)c * 8192 + t0 + tbase + a * 16 + row];
          __hip_bfloat16 h = __float2bfloat16(x);
          u.s[j] = *reinterpret_cast<short*>(&h);
        }
        afrag[a][cs] = u.v;
      }
  }

  const uint4* cbsrc = (const uint4*)(CBb + (size_t)m * 1048576);
  const float* bvbase = B32 + m * 4096;
  auto stage = [&](int g, int b) {     // async: group g (16KB) -> Bt[b]; 4 loads/wave
    const uint4* s = cbsrc + (size_t)(kt0 + 2 * g) * 512;
    uint4* db = (uint4*)Bt[b];
#pragma unroll
    for (int h = 0; h < 4; ++h) {
      int c0 = h * 256 + w * 64;       // wave-uniform 1KB window; lane offset = l*16B (HW)
      __builtin_amdgcn_global_load_lds(
          (const __attribute__((address_space(1))) void*)(s + c0 + l),
          (__attribute__((address_space(3))) void*)(db + c0),
          16, 0, 0);
    }
  };

  float rmin[16];
#pragma unroll
  for (int sl = 0; sl < 16; ++sl) rmin[sl] = FINF;
  stage(0, 0); stage(1, 1);
  asm volatile("s_waitcnt vmcnt(4)" ::: "memory");   // group 0 resident
  __builtin_amdgcn_s_barrier();                      // also covers umin init
  for (int p = 0; p < 64; ++p) {
    int b = p % 3;
    if (p + 2 < 64) stage(p + 2, (p + 2) % 3);       // buf free since phase-p barrier
#pragma unroll
    for (int t = 0; t < 2; ++t) {
      int kt = kt0 + 2 * p + t;
      float Bv = bvbase[kt * 16 + row];
      f32x4 acc[4];
#pragma unroll
      for (int a = 0; a < 4; ++a) acc[a] = f32x4{0.f,0.f,0.f,0.f};
#pragma unroll
      for (int cs = 0; cs < 8; ++cs) {
        bf16x8 bf = *(const bf16x8*)&Bt[b][t * 4096 + cs * 512 + l * 8];
#pragma unroll
        for (int a = 0; a < 4; ++a)
          acc[a] = __builtin_amdgcn_mfma_f32_16x16x32_bf16(afrag[a][cs], bf, acc[a], 0, 0, 0);
      }
#pragma unroll
      for (int a = 0; a < 4; ++a)
#pragma unroll
        for (int r = 0; r < 4; ++r)
          rmin[a * 4 + r] = fminf(rmin[a * 4 + r], fmaf(-2.0f, acc[a][r], Bv));
    }
    if (p < 62) {                      // counted: group p+1 landed, p+2 may still fly
      asm volatile("s_waitcnt vmcnt(4)" ::: "memory");
      __builtin_amdgcn_s_barrier();
    } else if (p == 62) {
      asm volatile("s_waitcnt vmcnt(0)" ::: "memory");
      __builtin_amdgcn_s_barrier();
    }
  }
#pragma unroll
  for (int a = 0; a < 4; ++a)
#pragma unroll
    for (int r = 0; r < 4; ++r)
      atomicMin(&umin[tbase + a * 16 + grp * 4 + r], fkey(rmin[a * 4 + r]));
  __syncthreads();
  atomicMin(&gumin[(size_t)(t0 + tid) * 8 + m], umin[tid]);
}

// ---------- scan pass B: recompute vs FINAL threshold, 64 tok/wave, counted-vmcnt ----------
__global__ __launch_bounds__(256, 2) void k_scanB(const float* __restrict__ XH,
                                                  const unsigned short* __restrict__ CBb,
                                                  const float* __restrict__ B32,
                                                  const unsigned int* __restrict__ gumin,
                                                  int* __restrict__ cnts,
                                                  unsigned short* __restrict__ lists) {
  int bx = blockIdx.x;
  int m = bx & 7, ks = (bx >> 3) & 1, tt = bx >> 4;
  int t0 = tt * 256, kt0 = ks * 128;
  __shared__ unsigned short Bt[3][2 * 4096];   // 48KB
  __shared__ int lcnt[256];
  __shared__ unsigned short llist[256][16];
  int tid = threadIdx.x;
  lcnt[tid] = 0;
  int w = tid >> 6, l = tid & 63;
  int row = l & 15, grp = l >> 4;
  int tbase = w * 64;

  bf16x8 afrag[4][8];
  {
    const float* xbase = XH + (size_t)m * 2097152;
#pragma unroll
    for (int a = 0; a < 4; ++a)
#pragma unroll
      for (int cs = 0; cs < 8; ++cs) {
        union { short s[8]; bf16x8 v; } u;
#pragma unroll
        for (int j = 0; j < 8; ++j) {
          int c = cs * 32 + grp * 8 + j;
          float x = xbase[(size_t)c * 8192 + t0 + tbase + a * 16 + row];
          __hip_bfloat16 h = __float2bfloat16(x);
          u.s[j] = *reinterpret_cast<short*>(&h);
        }
        afrag[a][cs] = u.v;
      }
  }
  float thr[16];
#pragma unroll
  for (int a = 0; a < 4; ++a)
#pragma unroll
    for (int r = 0; r < 4; ++r) {
      int tok = t0 + tbase + a * 16 + grp * 4 + r;
      thr[a * 4 + r] = funkey(gumin[(size_t)tok * 8 + m]) + DELTA;   // final (post-scanA)
    }

  const uint4* cbsrc = (const uint4*)(CBb + (size_t)m * 1048576);
  const float* bvbase = B32 + m * 4096;
  auto stage = [&](int g, int b) {
    const uint4* s = cbsrc + (size_t)(kt0 + 2 * g) * 512;
    uint4* db = (uint4*)Bt[b];
#pragma unroll
    for (int h = 0; h < 4; ++h) {
      int c0 = h * 256 + w * 64;
      __builtin_amdgcn_global_load_lds(
          (const __attribute__((address_space(1))) void*)(s + c0 + l),
          (__attribute__((address_space(3))) void*)(db + c0),
          16, 0, 0);
    }
  };

  stage(0, 0); stage(1, 1);
  asm volatile("s_waitcnt vmcnt(4)" ::: "memory");
  __builtin_amdgcn_s_barrier();                      // also covers lcnt init
  for (int p = 0; p < 64; ++p) {
    int b = p % 3;
    if (p + 2 < 64) stage(p + 2, (p + 2) % 3);
#pragma unroll
    for (int t = 0; t < 2; ++t) {
      int kt = kt0 + 2 * p + t;
      float Bv = bvbase[kt * 16 + row];
      f32x4 acc[4];
#pragma unroll
      for (int a = 0; a < 4; ++a) acc[a] = f32x4{0.f,0.f,0.f,0.f};
#pragma unroll
      for (int cs = 0; cs < 8; ++cs) {
        bf16x8 bf = *(const bf16x8*)&Bt[b][t * 4096 + cs * 512 + l * 8];
#pragma unroll
        for (int a = 0; a < 4; ++a)
          acc[a] = __builtin_amdgcn_mfma_f32_16x16x32_bf16(afrag[a][cs], bf, acc[a], 0, 0, 0);
      }
      int k = (kt << 4) + row;
#pragma unroll
      for (int a = 0; a < 4; ++a)
#pragma unroll
        for (int r = 0; r < 4; ++r) {
          float s = fmaf(-2.0f, acc[a][r], Bv);
          if (s <= thr[a * 4 + r]) {
            int tok = tbase + a * 16 + grp * 4 + r;
            int pos = atomicAdd(&lcnt[tok], 1);
            if (pos < 16) llist[tok][pos] = (unsigned short)k;
          }
        }
    }
    if (p < 62) {
      asm volatile("s_waitcnt vmcnt(4)" ::: "memory");
      __builtin_amdgcn_s_barrier();
    } else if (p == 62) {
      asm volatile("s_waitcnt vmcnt(0)" ::: "memory");
      __builtin_amdgcn_s_barrier();
    }
  }
  __syncthreads();                     // all inserts visible before flush
  // flush: accumulate into global cnts/lists (two ks-blocks share each token)
  {
    int n = lcnt[tid];
    if (n > 0) {
      size_t t8m = (size_t)(t0 + tid) * 8 + m;
      int base = atomicAdd(&cnts[t8m], n);
      int nc = n < 16 ? n : 16;
      for (int i = 0; i < nc && base + i < 16; ++i)
        lists[t8m * 16 + base + i] = llist[tid][i];
    }
  }
}

// ---------- np-f32-exact final selection among candidates ----------
__global__ __launch_bounds__(256) void k_select(const float* __restrict__ XH,
                                                const float* __restrict__ cb,
                                                const float* __restrict__ B32,
                                                const int* __restrict__ cnts,
                                                const unsigned short* __restrict__ lists,
                                                int* __restrict__ idxp) {
#pragma clang fp contract(off)
  int bx = blockIdx.x;                 // grid 1024 = tt(128) * m(8)
  int m = bx & 7, tt = bx >> 3;
  int t0 = tt * 64;
  __shared__ float XT2[256 * 65];      // padded [c][t]
  __shared__ float Atok[64];
  __shared__ int ovlist[64];
  __shared__ int ovcnt;
  __shared__ float bvD[64];
  __shared__ int bvK[64];
  int tid = threadIdx.x;
  const float* xsrc = XH + (size_t)m * 2097152;
#pragma unroll
  for (int i = 0; i < 16; ++i) {
    int f = tid + 256 * i;
    int c = f >> 4, to = (f & 15) * 4;
    f32x4 v = *(const f32x4*)(xsrc + (size_t)c * 8192 + t0 + to);
    XT2[c*65+to+0]=v[0]; XT2[c*65+to+1]=v[1]; XT2[c*65+to+2]=v[2]; XT2[c*65+to+3]=v[3];
  }
  if (tid == 0) ovcnt = 0;
  __syncthreads();
  if (tid < 64) Atok[tid] = np_pw256sq(&XT2[tid], 65);   // np.sum(x*x) emulation
  __syncthreads();
  int q = tid >> 2, j = tid & 3;       // 64 quads (token t0+q) x 4 SSE lanes
  const float* cbm = cb + (size_t)m * 1048576;

  auto dist_np = [&](int k, int qq, float A) -> float {
#pragma clang fp contract(off)
    const float* row = cbm + (size_t)k * 256;
    float s = 0.0f;
    for (int i8 = 0; i8 < 256; i8 += 8) {
      float p0 = XT2[(i8 + j) * 65 + qq] * row[i8 + j];
      s = s + p0;
      float p1 = XT2[(i8 + 4 + j) * 65 + qq] * row[i8 + 4 + j];
      s = s + p1;
    }
    float o  = __shfl_xor(s, 1, 64);
    float ts = s + o;
    float o2 = __shfl_xor(ts, 2, 64);
    float red = ts + o2;               // (s0+s1)+(s2+s3)
    float T1 = A + B32[m * 4096 + k];  // fl(A + Bk)
    return T1 - 2.0f * red;            // fl(T1 - fl(2E))
  };

  int t8m = (t0 + q) * 8 + m;
  int n = cnts[t8m];
  float A = Atok[q];
  if (n <= 16) {
    float best = __builtin_inff();
    int bk = 0;
    for (int ci = 0; ci < n; ++ci) {
      int k = (int)lists[(size_t)t8m * 16 + ci] & 4095;
      float d2 = dist_np(k, q, A);
      if (d2 < best || (d2 == best && k < bk)) { best = d2; bk = k; }
    }
    if (j == 0) idxp[t8m] = bk;
  } else {
    if (j == 0) { int pos = atomicAdd(&ovcnt, 1); ovlist[pos] = q; }
  }
  __syncthreads();
  int ovn = ovcnt;
  for (int e = 0; e < ovn; ++e) {      // block-cooperative full scan per overflow token
    int qq = ovlist[e];
    float Aq = Atok[qq];
    float bd = __builtin_inff(); int bk2 = 0;
    for (int it = 0; it < 64; ++it) {
      int k = it * 64 + q;
      float d2 = dist_np(k, qq, Aq);
      if (d2 < bd) { bd = d2; bk2 = k; }
    }
    if (j == 0) { bvD[q] = bd; bvK[q] = bk2; }
    __syncthreads();
    if (tid == 0) {
      float bb = bvD[0]; int kk2 = bvK[0];
      for (int r = 1; r < 64; ++r) {
        if (bvD[r] < bb || (bvD[r] == bb && bvK[r] < kk2)) { bb = bvD[r]; kk2 = bvK[r]; }
      }
      idxp[(t0 + qq) * 8 + m] = kk2;
    }
    __syncthreads();
  }
}

// ---------- out = q@Wo + bo via bf16 MFMA (tolerance-safe), + f32 loss partials ----------
// grid 512 = tt(64) * m(8); block = 4 waves x 32 toks = 128 tokens; 16 d-tiles
__global__ __launch_bounds__(256, 2) void k_out(const float* __restrict__ cb,
                                                const unsigned short* __restrict__ WoT,
                                                const float* __restrict__ bo,
                                                const float* __restrict__ XH,
                                                const int* __restrict__ idxp,
                                                float* __restrict__ outp,
                                                double* __restrict__ lossp) {
  int bx = blockIdx.x;
  int m = bx & 7, tt = bx >> 3;
  int t0 = tt * 128;
  __shared__ unsigned short Bt[3][4096];   // 3 bufs x 8KB
  __shared__ double red[256];
  int tid = threadIdx.x;
  int w = tid >> 6, l = tid & 63;
  int row = l & 15, grp = l >> 4;
  int tw = w * 32;

  // A-fragments: q rows (bf16) gathered from cb via idx
  bf16x8 afrag[2][8];
#pragma unroll
  for (int a = 0; a < 2; ++a) {
    int tok = t0 + tw + a * 16 + row;
    int ix = idxp[(size_t)tok * 8 + m] & 4095;
    const float* qrow = cb + (size_t)m * 1048576 + (size_t)ix * 256;
#pragma unroll
    for (int cs = 0; cs < 8; ++cs) {
      union { short s[8]; bf16x8 v; } u;
#pragma unroll
      for (int j = 0; j < 8; ++j) {
        float v = qrow[cs * 32 + grp * 8 + j];
        __hip_bfloat16 h = __float2bfloat16(v);
        u.s[j] = *reinterpret_cast<short*>(&h);
      }
      afrag[a][cs] = u.v;
    }
  }

  const uint4* wsrc = (const uint4*)(WoT + (size_t)m * 65536);
  auto stage = [&](int dtile, int b) {     // 8KB tile -> Bt[b]; 2 loads/wave
    const uint4* s = wsrc + (size_t)dtile * 512;
    uint4* db = (uint4*)Bt[b];
#pragma unroll
    for (int h = 0; h < 2; ++h) {
      int c0 = h * 256 + w * 64;
      __builtin_amdgcn_global_load_lds(
          (const __attribute__((address_space(1))) void*)(s + c0 + l),
          (__attribute__((address_space(3))) void*)(db + c0),
          16, 0, 0);
    }
  };

  stage(0, 0); stage(1, 1);
  asm volatile("s_waitcnt vmcnt(2)" ::: "memory");   // tile 0 resident
  __builtin_amdgcn_s_barrier();
  for (int dt = 0; dt < 16; ++dt) {
    int b = dt % 3;
    if (dt + 2 < 16) stage(dt + 2, (dt + 2) % 3);
    f32x4 acc[2];
#pragma unroll
    for (int a = 0; a < 2; ++a) acc[a] = f32x4{0.f,0.f,0.f,0.f};
#pragma unroll
    for (int cs = 0; cs < 8; ++cs) {
      bf16x8 bf = *(const bf16x8*)&Bt[b][cs * 512 + l * 8];
#pragma unroll
      for (int a = 0; a < 2; ++a)
        acc[a] = __builtin_amdgcn_mfma_f32_16x16x32_bf16(afrag[a][cs], bf, acc[a], 0, 0, 0);
    }
    float bov = bo[m * 256 + dt * 16 + row];
#pragma unroll
    for (int a = 0; a < 2; ++a)
#pragma unroll
      for (int r = 0; r < 4; ++r)
        outp[(size_t)(t0 + tw + a * 16 + grp * 4 + r) * 2048 + m * 256 + dt * 16 + row] =
            acc[a][r] + bov;
    if (dt < 14) {
      asm volatile("s_waitcnt vmcnt(2)" ::: "memory");
      __builtin_amdgcn_s_barrier();
    } else if (dt == 14) {
      asm volatile("s_waitcnt vmcnt(0)" ::: "memory");
      __builtin_amdgcn_s_barrier();
    }
  }

  // loss partials (f32, same numerics class as before): 2 threads per token
  {
    int tok = tid >> 1, half = tid & 1;
    int gt = t0 + tok;
    int ix = idxp[(size_t)gt * 8 + m] & 4095;
    const float* qrow = cb + (size_t)m * 1048576 + (size_t)ix * 256 + half * 128;
    const float* xcol = XH + (size_t)m * 2097152 + (size_t)(half * 128) * 8192 + gt;
    float lp = 0.0f;
    for (int c = 0; c < 128; ++c) {
      float d = qrow[c] - xcol[(size_t)c * 8192];
      lp += d * d;
    }
    red[tid] = (double)lp;
  }
  __syncthreads();
  for (int off = 128; off; off >>= 1) { if (tid < off) red[tid] += red[tid + off]; __syncthreads(); }
  if (tid == 0) lossp[bx] = red[0];
}

// ---------- finalize loss (f32 at outp[16777216]) ----------
__global__ void k_final(const double* __restrict__ lossp, float* __restrict__ outp) {
  __shared__ double red[256];
  int tid = threadIdx.x;
  double s = 0.0;
  for (int i = 0; i < 2; ++i) s += lossp[tid + 256 * i];   // 512 partials (k_out grid)
  red[tid] = s; __syncthreads();
  for (int off = 128; off; off >>= 1) { if (tid < off) red[tid] += red[tid + off]; __syncthreads(); }
  if (tid == 0) outp[16777216] = (float)(1.25 * red[0] / 16777216.0);
}

// ---------- idx -> f32 ----------
__global__ void k_idxout(const int* __restrict__ idxp, float* __restrict__ outp) {
  int i = blockIdx.x * 256 + threadIdx.x;
  outp[16777217 + i] = (float)idxp[i];
}

extern "C" void kernel_launch(void* const* d_in, const int* in_sizes, int n_in,
                              void* d_out, int out_size, void* d_ws, size_t ws_size,
                              hipStream_t stream) {
  (void)in_sizes; (void)n_in; (void)out_size; (void)ws_size;
  const float* slots = (const float*)d_in[0];
  const float* Wp    = (const float*)d_in[1];
  const float* bp    = (const float*)d_in[2];
  const float* cb    = (const float*)d_in[3];
  const float* Wo    = (const float*)d_in[4];
  const float* bo    = (const float*)d_in[5];
  float* outp = (float*)d_out;
  char* ws = (char*)d_ws;
  double*         lossp = (double*)(ws + WS_LOSSP);
  unsigned int*   gumin = (unsigned int*)(ws + WS_UMIN);
  float*          B32   = (float*)(ws + WS_B32);
  int*            idxp  = (int*)(ws + WS_IDX);
  int*            cnts  = (int*)(ws + WS_CNT);
  unsigned short* lists = (unsigned short*)(ws + WS_LST);
  float*          XH    = (float*)(ws + WS_XH);
  unsigned short* CBb   = (unsigned short*)(ws + WS_CBT);
  unsigned short* WoTb  = (unsigned short*)(ws + WS_WOT);

  hipMemsetAsync(gumin, 0xFF, 65536 * sizeof(unsigned int), stream);
  hipMemsetAsync(cnts,  0,    65536 * sizeof(int), stream);
  k_cbnormB<<<128,  256, 0, stream>>>(cb, B32);
  k_cbb    <<<2048, 256, 0, stream>>>(cb, CBb);
  k_wot    <<<128,  256, 0, stream>>>(Wo, WoTb);
  k_xhat   <<<4096, 256, 0, stream>>>(slots, Wp, bp, XH);
  k_scanA  <<<512,  256, 0, stream>>>(XH, CBb, B32, gumin);
  k_scanB  <<<512,  256, 0, stream>>>(XH, CBb, B32, gumin, cnts, lists);
  k_select <<<1024, 256, 0, stream>>>(XH, cb, B32, cnts, lists, idxp);
  k_out    <<<512,  256, 0, stream>>>(cb, WoTb, bo, XH, idxp, outp, lossp);
  k_final  <<<1,    256, 0, stream>>>(lossp, outp);
  k_idxout <<<256,  256, 0, stream>>>(idxp, outp);
}